// Round 13
// baseline (414.649 us; speedup 1.0000x reference)
//
#include <hip/hip_runtime.h>
#include <hip/hip_bf16.h>

#define TOK  4096
#define DIMD 1024
#define NEXP 8
#define DFFN 4096
#define NSLOT   (TOK*2 + NEXP*128)       /* 9216 padded slots (128-aligned bases) */
#define NRB128  ((TOK*2)/128 + NEXP)     /* 72 worst-case 128-rowblocks */

typedef __attribute__((ext_vector_type(8))) short bf16x8;
typedef __attribute__((ext_vector_type(4))) float f32x4;

__device__ __forceinline__ unsigned short f2bf(float f){
  unsigned int u = __float_as_uint(f);
  unsigned int r = u + 0x7FFFu + ((u >> 16) & 1u);   // RNE (finite values only here)
  return (unsigned short)(r >> 16);
}

__device__ __forceinline__ float bf2f(unsigned short h){
  unsigned int u = ((unsigned int)h) << 16;
  return __uint_as_float(u);
}

__device__ __forceinline__ void gload_lds16(const void* g, void* l){
  __builtin_amdgcn_global_load_lds(
      (const __attribute__((address_space(1))) unsigned int*)g,
      (__attribute__((address_space(3))) unsigned int*)l, 16, 0, 0);
}

// ---------------- gating: one wave per token, fused x->bf16 ----------------
// R13: the W1 transpose is GONE (GEMM1 stages B directly from fp32 W1 with
// in-register convert into the same swizzled LDS layout). Dispatch 1 = gating only.
__global__ __launch_bounds__(256) void k_gate(
    const float* __restrict__ x, const float* __restrict__ Wg,
    const float* __restrict__ bg, int* __restrict__ topidx,
    float* __restrict__ topw, int* __restrict__ pos, int* __restrict__ count,
    unsigned short* __restrict__ xb)
{
  const int gb = blockIdx.x;
  const int wid = threadIdx.x >> 6, lane = threadIdx.x & 63;
  const int t = gb * 4 + wid;
  const float* xr = x + (size_t)t * DIMD;
  unsigned short* xbr = xb + (size_t)t * DIMD;
  float acc[NEXP] = {0.f,0.f,0.f,0.f,0.f,0.f,0.f,0.f};
  #pragma unroll
  for (int j = 0; j < DIMD/64; ++j){
    const int d = j*64 + lane;
    const float xv = xr[d];
    xbr[d] = f2bf(xv);                       // fused bf16 conversion
    const float4 wa = *(const float4*)(Wg + (size_t)d*NEXP);
    const float4 wb = *(const float4*)(Wg + (size_t)d*NEXP + 4);
    acc[0] += xv*wa.x; acc[1] += xv*wa.y; acc[2] += xv*wa.z; acc[3] += xv*wa.w;
    acc[4] += xv*wb.x; acc[5] += xv*wb.y; acc[6] += xv*wb.z; acc[7] += xv*wb.w;
  }
  #pragma unroll
  for (int e = 0; e < NEXP; ++e){
    float v = acc[e];
    #pragma unroll
    for (int o = 32; o > 0; o >>= 1) v += __shfl_xor(v, o);
    acc[e] = v;
  }
  if (lane == 0){
    float lg[NEXP], m = -1e30f;
    #pragma unroll
    for (int e = 0; e < NEXP; ++e){ lg[e] = acc[e] + bg[e]; m = fmaxf(m, lg[e]); }
    float p[NEXP], S = 0.f;
    #pragma unroll
    for (int e = 0; e < NEXP; ++e){ p[e] = expf(lg[e] - m); S += p[e]; }
    int e0 = 0;
    #pragma unroll
    for (int e = 1; e < NEXP; ++e) if (p[e] > p[e0]) e0 = e;
    int e1 = (e0 == 0) ? 1 : 0;
    #pragma unroll
    for (int e = 0; e < NEXP; ++e){
      if (e == e0 || e == e1) continue;
      if (p[e] > p[e1]) e1 = e;
    }
    const float denom = p[e0] + p[e1] + 1e-8f * S;   // == top_sum + EPS, scaled by S
    const float w0 = p[e0] / denom, w1 = p[e1] / denom;
    const int p0 = atomicAdd(&count[e0], 1);
    const int p1 = atomicAdd(&count[e1], 1);
    topidx[t*2] = e0; topidx[t*2+1] = e1;
    topw[t*2] = w0;   topw[t*2+1] = w1;
    pos[t*2] = p0;    pos[t*2+1] = p1;
  }
}

// scatter with inline prefix-scan of count (128-aligned padded bases)
__global__ __launch_bounds__(256) void k_scatter(
    const int* __restrict__ topidx, const int* __restrict__ pos,
    const int* __restrict__ count, int* __restrict__ slot_of, int* __restrict__ tok_of)
{
  int basee[NEXP]; int bacc = 0;
  #pragma unroll
  for (int q = 0; q < NEXP; ++q){
    basee[q] = bacc << 7;
    bacc += (count[q] + 127) >> 7;
  }
  const int t = blockIdx.x * 256 + threadIdx.x;
  #pragma unroll
  for (int k = 0; k < 2; ++k){
    const int e = topidx[t*2+k];
    const int g = basee[e] + pos[t*2+k];
    slot_of[t*2+k] = g;
    tok_of[g] = t;
  }
}

// ---------- MFMA GEMM: BM x BN tile, BK=64, 8 waves, single-buffer (R2-proven) ----------
// Expert-chunk XCD mapping (validated R7/R8/R9/R12 via FETCH A/B: XCD ~ hw_id%8).
// R13 (BF32=1, GEMM1): B staged DIRECTLY from fp32 W1 [K][N] row-major — wave w
// loads k-rows 8w..8w+7 (8x float4/lane, 1KB/wave coalesced), f2bf in-register,
// ds_write_b128 into the SAME swizzled sB layout (k-octet w at chunk w^(n&7));
// fragment reads (boff) untouched; sB contents bit-identical to the old transpose
// path (same f2bf on same values). Eliminates w1t + the 152us transpose dispatch.
// TRW2=1 fuses the W2 transpose as extra blocks (by >= NRB128) — R7.
// MODE 1: A gathered via tok_of, epilogue bias+GELU -> bf16 outH
// MODE 2: A slot-contiguous, split-K, bias(ks==0) -> Ys0/Ys1
template<int KD, int KSLICES, int NT, int MODE, int WAVES, int BM, int BN, int MINW,
         int TRW2, int BF32>
__global__ __launch_bounds__(WAVES*64, MINW) void k_gemm(
    const unsigned short* __restrict__ A, const unsigned short* __restrict__ Bt,
    const float* __restrict__ bias, const int* __restrict__ tok_of,
    const int* __restrict__ count,
    unsigned short* __restrict__ outH, unsigned short* __restrict__ outY,
    unsigned short* __restrict__ outY1,
    const float* __restrict__ W2src, unsigned short* __restrict__ w2tdst,
    const float* __restrict__ Bf32)
{
  __shared__ alignas(16) unsigned short smem[BM*64 + BN*64];   // 48KB, both roles
  constexpr int CT = NT / BN;          // ct values (16 GEMM1, 4 GEMM2)

  int by, ct, ks;
  if constexpr (TRW2 != 0){
    by = blockIdx.y;
    if (by >= NRB128){
      // ---- W2 transpose role: one 128x128 tile, 512 threads ----
      const int bid = (by - NRB128) * gridDim.x + blockIdx.x;    // 0..2047
      const int eT = bid >> 8, rem = bid & 255;
      const int R = DFFN, C = DIMD;         // W2: [4096][1024] -> w2t [1024][4096]
      const float* I = W2src + (size_t)eT * R * C;
      unsigned short* O = w2tdst + (size_t)eT * R * C;
      const int r0 = (rem >> 3) * 128, c0 = (rem & 7) * 128;     // 32 x 8 tiles
      unsigned short* tile = smem;          // 32KB of the 48KB block
      const int tid = threadIdx.x;
      const int qw = tid & 31, rw = tid >> 5;   // rw 0..15
      #pragma unroll
      for (int it = 0; it < 8; ++it){
        const int r = it * 16 + rw;
        const float4 v = *(const float4*)(I + (size_t)(r0 + r) * C + c0 + qw * 4);
        ushort4 o;
        o.x = f2bf(v.x); o.y = f2bf(v.y); o.z = f2bf(v.z); o.w = f2bf(v.w);
        const int slot = qw ^ ((r >> 2) & 31);
        *(ushort4*)&tile[r * 128 + slot * 4] = o;
      }
      __syncthreads();
      const int p = tid & 31, cb = tid >> 5;    // cb 0..15
      #pragma unroll
      for (int it = 0; it < 2; ++it){
        const int cg = cb * 2 + it;             // 0..31
        const int sl = (cg ^ p) * 4;
        const ushort4 a0 = *(const ushort4*)&tile[(4*p + 0) * 128 + sl];
        const ushort4 a1 = *(const ushort4*)&tile[(4*p + 1) * 128 + sl];
        const ushort4 a2 = *(const ushort4*)&tile[(4*p + 2) * 128 + sl];
        const ushort4 a3 = *(const ushort4*)&tile[(4*p + 3) * 128 + sl];
        ushort4 o;
        o.x = a0.x; o.y = a1.x; o.z = a2.x; o.w = a3.x;
        *(ushort4*)(O + (size_t)(c0 + 4*cg + 0) * R + r0 + 4*p) = o;
        o.x = a0.y; o.y = a1.y; o.z = a2.y; o.w = a3.y;
        *(ushort4*)(O + (size_t)(c0 + 4*cg + 1) * R + r0 + 4*p) = o;
        o.x = a0.z; o.y = a1.z; o.z = a2.z; o.w = a3.z;
        *(ushort4*)(O + (size_t)(c0 + 4*cg + 2) * R + r0 + 4*p) = o;
        o.x = a0.w; o.y = a1.w; o.z = a2.w; o.w = a3.w;
        *(ushort4*)(O + (size_t)(c0 + 4*cg + 3) * R + r0 + 4*p) = o;
      }
      return;
    }
    // GEMM1 role: expert-chunk XCD mapping. g in [0, 1152), hw XCD = g%8 = by/9.
    const int g = blockIdx.x + (int)gridDim.x * by;
    by = 9 * (g & 7) + ((g % 72) >> 3);
    ct = g / 72;
    ks = 0;
  } else {
    // GEMM2 role: 1D grid CT*NRB128*KSLICES (=576), expert-chunk XCD mapping.
    static_assert(CT * KSLICES == 8, "GEMM2 map assumes 8 blocks per rowblock");
    const int g = blockIdx.x;
    const int xx = g & 7;
    const int w  = g >> 3;            // [0, 72)
    by = 9 * xx + (w % 9);
    const int cw = w / 9;             // [0, 8)
    ct = cw % CT;
    ks = cw / CT;
  }

  // ---- GEMM role ----
  int e = -1, b0 = 0;
  #pragma unroll
  for (int q = 0; q < NEXP; ++q){
    const int nb = (count[q] + 127) >> 7;
    if (e < 0){ if (by < b0 + nb) e = q; else b0 += nb; }
  }
  if (e < 0) return;
  constexpr int KSL = KD / KSLICES;     // K elements per slice (multiple of 64)
  const int kbase = ks * KSL;
  const int row0 = by * 128;        // global padded slot row (pad-contiguous layout)
  constexpr int T   = WAVES * 64;   // threads
  constexpr int RA  = BM*8 / T;     // A staging rounds
  constexpr int RB  = BN*8 / T;     // B staging rounds (bf16 path)
  constexpr int WN  = BN / 64;      // wave-columns (64-wide)
  constexpr int WM  = WAVES / WN;   // wave-rows
  constexpr int MR  = BM / WM / 16; // 16-row fragment repeats per wave
  unsigned short* sA = smem;
  unsigned short* sB = smem + BM*64;
  const int tid = threadIdx.x, wid = tid >> 6, lane = tid & 63;

  // staging: slot s covers row s>>3, global chunk (s&7)^(row&7)
  const unsigned short* aptr[RA];
  #pragma unroll
  for (int i = 0; i < RA; ++i){
    const int s = i*T + tid;
    const int row = s >> 3;
    const int c = (s & 7) ^ (row & 7);
    size_t arow;
    if (MODE == 1) arow = (size_t)tok_of[row0 + row] * KD;
    else           arow = (size_t)(row0 + row) * KD;
    aptr[i] = A + arow + kbase + c*8;
  }
  const unsigned short* bptr[RB];
  if constexpr (BF32 == 0){
    #pragma unroll
    for (int i = 0; i < RB; ++i){
      const int s = i*T + tid;
      const int row = s >> 3;
      const int c = (s & 7) ^ (row & 7);
      bptr[i] = Bt + ((size_t)e*NT + ct*BN + row) * KD + kbase + c*8;
    }
  }
  // fp32 B source (GEMM1): wave wid covers k-rows 8*wid..8*wid+7; lane covers
  // n-cols 4*lane..4*lane+3 of the 256-wide tile. 1KB contiguous per wave-load.
  const float* bfp = nullptr;
  if constexpr (BF32 != 0)
    bfp = Bf32 + ((size_t)e*KD + kbase + 8*wid) * NT + ct*BN + 4*lane;

  f32x4 acc[MR][4] = {};
  const int wr = wid / WN, wc = wid % WN;   // wave tile (MR*16) x 64

  int aoff[MR][2], boff[4][2];
  #pragma unroll
  for (int m = 0; m < MR; ++m){
    #pragma unroll
    for (int s = 0; s < 2; ++s){
      const int rowA = wr*(MR*16) + m*16 + (lane & 15);
      aoff[m][s] = rowA*64 + (((s*4) + (lane >> 4)) ^ (rowA & 7))*8;
    }
  }
  #pragma unroll
  for (int n = 0; n < 4; ++n){
    #pragma unroll
    for (int s = 0; s < 2; ++s){
      const int rowB = wc*64 + n*16 + (lane & 15);
      boff[n][s] = rowB*64 + (((s*4) + (lane >> 4)) ^ (rowB & 7))*8;
    }
  }

  for (int k0 = 0; k0 < KSL; k0 += 64){
    if constexpr (BF32 != 0){
      float4 bv[8];
      const float* bp = bfp + (size_t)k0 * NT;
      #pragma unroll
      for (int r = 0; r < 8; ++r) bv[r] = *(const float4*)(bp + (size_t)r * NT);
      #pragma unroll
      for (int i = 0; i < RA; ++i)
        gload_lds16(aptr[i] + k0, &sA[(i*T + tid - lane)*8]);
      #pragma unroll
      for (int j = 0; j < 4; ++j){
        bf16x8 col;
        #pragma unroll
        for (int r = 0; r < 8; ++r)
          col[r] = (short)f2bf(((const float*)&bv[r])[j]);
        const int n = 4*lane + j;
        *(bf16x8*)&sB[n*64 + ((wid ^ (n & 7)))*8] = col;
      }
    } else {
      #pragma unroll
      for (int i = 0; i < RA; ++i)
        gload_lds16(aptr[i] + k0, &sA[(i*T + tid - lane)*8]);
      #pragma unroll
      for (int i = 0; i < RB; ++i)
        gload_lds16(bptr[i] + k0, &sB[(i*T + tid - lane)*8]);
    }
    __syncthreads();
    #pragma unroll
    for (int s = 0; s < 2; ++s){
      bf16x8 af[MR], bfr[4];
      #pragma unroll
      for (int m = 0; m < MR; ++m) af[m] = *(const bf16x8*)&sA[aoff[m][s]];
      #pragma unroll
      for (int n = 0; n < 4; ++n) bfr[n] = *(const bf16x8*)&sB[boff[n][s]];
      #pragma unroll
      for (int m = 0; m < MR; ++m)
        #pragma unroll
        for (int n = 0; n < 4; ++n)
          acc[m][n] = __builtin_amdgcn_mfma_f32_16x16x32_bf16(af[m], bfr[n], acc[m][n], 0, 0, 0);
    }
    __syncthreads();
  }

  const float* be = bias + (size_t)e * NT;
  unsigned short* outYs = (ks == 0) ? outY : outY1;
  #pragma unroll
  for (int m = 0; m < MR; ++m){
    #pragma unroll
    for (int n = 0; n < 4; ++n){
      #pragma unroll
      for (int j = 0; j < 4; ++j){
        const int rl = wr*(MR*16) + m*16 + ((lane >> 4) << 2) + j;  // C row = (l>>4)*4+j
        const int ng = ct*BN + wc*64 + n*16 + (lane & 15);          // C col = l&15
        const size_t orow = (size_t)(row0 + rl) * NT + ng;          // pad rows: harmless
        if (MODE == 1){
          const float u = acc[m][n][j] + be[ng];
          // tanh-form GELU (|diff from exact| <~3e-3, << bf16 rounding of Hs)
          float y = 0.7978845608028654f * (u + 0.044715f * u * u * u);
          y = fminf(fmaxf(y, -15.f), 15.f);
          const float ex = __expf(2.f * y);
          const float th = (ex - 1.f) / (ex + 1.f);
          outH[orow] = f2bf(0.5f * u * (1.f + th));
        } else {
          outYs[orow] = f2bf(acc[m][n][j] + ((ks == 0) ? be[ng] : 0.f));
        }
      }
    }
  }
}

// ---------------- combine top-2 (sum bf16 split-K partials) + LayerNorm ----------------
__global__ __launch_bounds__(256) void k_combine_ln(
    const unsigned short* __restrict__ Ys0, const unsigned short* __restrict__ Ys1,
    const int* __restrict__ slot_of,
    const float* __restrict__ topw, const float* __restrict__ gamma,
    const float* __restrict__ beta, float* __restrict__ out)
{
  const int t = blockIdx.x;
  const int g0 = slot_of[t*2], g1 = slot_of[t*2+1];
  const float w0 = topw[t*2], w1 = topw[t*2+1];
  const int c = threadIdx.x;
  const ushort4 a0 = *(const ushort4*)(Ys0 + (size_t)g0*DIMD + c*4);
  const ushort4 a1 = *(const ushort4*)(Ys1 + (size_t)g0*DIMD + c*4);
  const ushort4 b0 = *(const ushort4*)(Ys0 + (size_t)g1*DIMD + c*4);
  const ushort4 b1 = *(const ushort4*)(Ys1 + (size_t)g1*DIMD + c*4);
  float4 v;
  v.x = w0*(bf2f(a0.x)+bf2f(a1.x)) + w1*(bf2f(b0.x)+bf2f(b1.x));
  v.y = w0*(bf2f(a0.y)+bf2f(a1.y)) + w1*(bf2f(b0.y)+bf2f(b1.y));
  v.z = w0*(bf2f(a0.z)+bf2f(a1.z)) + w1*(bf2f(b0.z)+bf2f(b1.z));
  v.w = w0*(bf2f(a0.w)+bf2f(a1.w)) + w1*(bf2f(b0.w)+bf2f(b1.w));
  float s  = v.x + v.y + v.z + v.w;
  float ss = v.x*v.x + v.y*v.y + v.z*v.z + v.w*v.w;
  #pragma unroll
  for (int o = 32; o > 0; o >>= 1){ s += __shfl_xor(s, o); ss += __shfl_xor(ss, o); }
  __shared__ float red[8];
  const int wid = threadIdx.x >> 6, lane = threadIdx.x & 63;
  if (lane == 0){ red[wid] = s; red[4 + wid] = ss; }
  __syncthreads();
  const float S  = red[0] + red[1] + red[2] + red[3];
  const float SS = red[4] + red[5] + red[6] + red[7];
  const float mu  = S * (1.f/DIMD);
  const float var = SS * (1.f/DIMD) - mu*mu;
  const float inv = rsqrtf(var + 1e-5f);
  const float4 gm = *(const float4*)(gamma + c*4);
  const float4 bt = *(const float4*)(beta + c*4);
  float4 o;
  o.x = (v.x - mu)*inv*gm.x + bt.x;
  o.y = (v.y - mu)*inv*gm.y + bt.y;
  o.z = (v.z - mu)*inv*gm.z + bt.z;
  o.w = (v.w - mu)*inv*gm.w + bt.w;
  *(float4*)(out + (size_t)t*DIMD + c*4) = o;
}

extern "C" void kernel_launch(void* const* d_in, const int* in_sizes, int n_in,
                              void* d_out, int out_size, void* d_ws, size_t ws_size,
                              hipStream_t stream)
{
  const float* x     = (const float*)d_in[0];
  const float* Wg    = (const float*)d_in[1];
  const float* bg    = (const float*)d_in[2];
  const float* W1    = (const float*)d_in[3];
  const float* b1    = (const float*)d_in[4];
  const float* W2    = (const float*)d_in[5];
  const float* b2    = (const float*)d_in[6];
  const float* gamma = (const float*)d_in[7];
  const float* beta  = (const float*)d_in[8];
  float* out = (float*)d_out;

  char* ws = (char*)d_ws;
  size_t off = 0;
  auto alloc = [&](size_t b){ char* p = ws + off; off += (b + 255) & ~(size_t)255; return p; };
  unsigned short* xb  = (unsigned short*)alloc((size_t)TOK*DIMD*2);
  unsigned short* Ys0b = (unsigned short*)alloc((size_t)NSLOT*DIMD*2);   // split-K partials
  unsigned short* Ys1b = (unsigned short*)alloc((size_t)NSLOT*DIMD*2);
  unsigned short* w2t = (unsigned short*)alloc((size_t)NEXP*DIMD*DFFN*2);
  unsigned short* Hs  = (unsigned short*)alloc((size_t)NSLOT*DFFN*2);
  int*   topidx  = (int*)alloc(TOK*2*4);
  float* topw    = (float*)alloc(TOK*2*4);
  int*   pos     = (int*)alloc(TOK*2*4);
  int*   slot_of = (int*)alloc(TOK*2*4);
  int*   tok_of  = (int*)alloc(NSLOT*4);
  int*   count   = (int*)alloc(256);

  (void)hipMemsetAsync(count, 0, NEXP*sizeof(int), stream);
  (void)hipMemsetAsync(tok_of, 0, NSLOT*sizeof(int), stream);  // pad rows -> token 0
  // Dispatch 1: gating only (W1 transpose eliminated — R13).
  k_gate<<<TOK/4, 256, 0, stream>>>(x, Wg, bg, topidx, topw, pos, count, xb);
  k_scatter<<<TOK/256, 256, 0, stream>>>(topidx, pos, count, slot_of, tok_of);
  // GEMM1 (by<72, expert-chunk XCD map, B from fp32 W1) + W2 transpose (by 72..199).
  k_gemm<DIMD, 1, DFFN, 1, 8, 128, 256, 3, 1, 1><<<dim3(DFFN/256, NRB128 + 128), 512, 0, stream>>>(
      xb, nullptr, b1, tok_of, count, Hs, nullptr, nullptr, W2, w2t, W1);
  // GEMM2: 1D grid 576, expert-chunk XCD map (R12).
  k_gemm<DFFN, 2, DIMD, 2, 8, 128, 256, 4, 0, 0><<<dim3((DIMD/256)*NRB128*2), 512, 0, stream>>>(
      Hs, w2t, b2, tok_of, count, nullptr, Ys0b, Ys1b, nullptr, nullptr, nullptr);
  k_combine_ln<<<TOK, 256, 0, stream>>>(Ys0b, Ys1b, slot_of, topw, gamma, beta, out);
}

// Round 14
// 411.611 us; speedup vs baseline: 1.0074x; 1.0074x over previous
//
#include <hip/hip_runtime.h>
#include <hip/hip_bf16.h>

#define TOK  4096
#define DIMD 1024
#define NEXP 8
#define DFFN 4096
#define NSLOT   (TOK*2 + NEXP*128)       /* 9216 padded slots (128-aligned bases) */
#define NRB128  ((TOK*2)/128 + NEXP)     /* 72 worst-case 128-rowblocks */

typedef __attribute__((ext_vector_type(8))) short bf16x8;
typedef __attribute__((ext_vector_type(4))) float f32x4;

__device__ __forceinline__ unsigned short f2bf(float f){
  unsigned int u = __float_as_uint(f);
  unsigned int r = u + 0x7FFFu + ((u >> 16) & 1u);   // RNE (finite values only here)
  return (unsigned short)(r >> 16);
}

__device__ __forceinline__ float bf2f(unsigned short h){
  unsigned int u = ((unsigned int)h) << 16;
  return __uint_as_float(u);
}

__device__ __forceinline__ void gload_lds16(const void* g, void* l){
  __builtin_amdgcn_global_load_lds(
      (const __attribute__((address_space(1))) unsigned int*)g,
      (__attribute__((address_space(3))) unsigned int*)l, 16, 0, 0);
}

// ---------------- gating: one wave per token, fused x->bf16 ----------------
__global__ __launch_bounds__(256) void k_gate(
    const float* __restrict__ x, const float* __restrict__ Wg,
    const float* __restrict__ bg, int* __restrict__ topidx,
    float* __restrict__ topw, int* __restrict__ pos, int* __restrict__ count,
    unsigned short* __restrict__ xb)
{
  const int gb = blockIdx.x;
  const int wid = threadIdx.x >> 6, lane = threadIdx.x & 63;
  const int t = gb * 4 + wid;
  const float* xr = x + (size_t)t * DIMD;
  unsigned short* xbr = xb + (size_t)t * DIMD;
  float acc[NEXP] = {0.f,0.f,0.f,0.f,0.f,0.f,0.f,0.f};
  #pragma unroll
  for (int j = 0; j < DIMD/64; ++j){
    const int d = j*64 + lane;
    const float xv = xr[d];
    xbr[d] = f2bf(xv);                       // fused bf16 conversion
    const float4 wa = *(const float4*)(Wg + (size_t)d*NEXP);
    const float4 wb = *(const float4*)(Wg + (size_t)d*NEXP + 4);
    acc[0] += xv*wa.x; acc[1] += xv*wa.y; acc[2] += xv*wa.z; acc[3] += xv*wa.w;
    acc[4] += xv*wb.x; acc[5] += xv*wb.y; acc[6] += xv*wb.z; acc[7] += xv*wb.w;
  }
  #pragma unroll
  for (int e = 0; e < NEXP; ++e){
    float v = acc[e];
    #pragma unroll
    for (int o = 32; o > 0; o >>= 1) v += __shfl_xor(v, o);
    acc[e] = v;
  }
  if (lane == 0){
    float lg[NEXP], m = -1e30f;
    #pragma unroll
    for (int e = 0; e < NEXP; ++e){ lg[e] = acc[e] + bg[e]; m = fmaxf(m, lg[e]); }
    float p[NEXP], S = 0.f;
    #pragma unroll
    for (int e = 0; e < NEXP; ++e){ p[e] = expf(lg[e] - m); S += p[e]; }
    int e0 = 0;
    #pragma unroll
    for (int e = 1; e < NEXP; ++e) if (p[e] > p[e0]) e0 = e;
    int e1 = (e0 == 0) ? 1 : 0;
    #pragma unroll
    for (int e = 0; e < NEXP; ++e){
      if (e == e0 || e == e1) continue;
      if (p[e] > p[e1]) e1 = e;
    }
    const float denom = p[e0] + p[e1] + 1e-8f * S;   // == top_sum + EPS, scaled by S
    const float w0 = p[e0] / denom, w1 = p[e1] / denom;
    const int p0 = atomicAdd(&count[e0], 1);
    const int p1 = atomicAdd(&count[e1], 1);
    topidx[t*2] = e0; topidx[t*2+1] = e1;
    topw[t*2] = w0;   topw[t*2+1] = w1;
    pos[t*2] = p0;    pos[t*2+1] = p1;
  }
}

// scatter with inline prefix-scan of count (128-aligned padded bases)
__global__ __launch_bounds__(256) void k_scatter(
    const int* __restrict__ topidx, const int* __restrict__ pos,
    const int* __restrict__ count, int* __restrict__ slot_of, int* __restrict__ tok_of)
{
  int basee[NEXP]; int bacc = 0;
  #pragma unroll
  for (int q = 0; q < NEXP; ++q){
    basee[q] = bacc << 7;
    bacc += (count[q] + 127) >> 7;
  }
  const int t = blockIdx.x * 256 + threadIdx.x;
  #pragma unroll
  for (int k = 0; k < 2; ++k){
    const int e = topidx[t*2+k];
    const int g = basee[e] + pos[t*2+k];
    slot_of[t*2+k] = g;
    tok_of[g] = t;
  }
}

// ---------- MFMA GEMM: BM x BN tile, BK=64, 8 waves, single-buffer (R2-proven) ----------
// Expert-chunk XCD mapping (validated R7/R8/R9/R12 via FETCH A/B: XCD ~ hw_id%8).
// BF32=1 (GEMM1): B staged directly from fp32 W1 [K][N] row-major — wave w loads
// k-rows 8w..8w+7 (8x float4/lane, 1KB/wave coalesced), f2bf in-register,
// ds_write_b128 into swizzled sB. R14 FIX: R13's sB swizzle sigma(n)=n&7 gave a
// 16-way write conflict (fixed j -> n&7 in {j,j+4} -> 2 bank groups; PMC 1.3e7).
// BF32 sB now uses sigma(n) = (n ^ (n>>2)) & 7: write side (n=4L+j) -> sigma is a
// bijection of L&7 -> all 8 bank groups (conflict-free); read side p=c^sigma(rowB)
// spans 8 values uniformly (8 lanes/group = min rounds). Write & read use the SAME
// sigma (both-sides rule) -> bit-identical results. GEMM2 path (BF32=0) unchanged.
// TRW2=1 fuses the W2 transpose as extra blocks (by >= NRB128) — R7.
// MODE 1: A gathered via tok_of, epilogue bias+GELU -> bf16 outH
// MODE 2: A slot-contiguous, split-K, bias(ks==0) -> Ys0/Ys1
template<int KD, int KSLICES, int NT, int MODE, int WAVES, int BM, int BN, int MINW,
         int TRW2, int BF32>
__global__ __launch_bounds__(WAVES*64, MINW) void k_gemm(
    const unsigned short* __restrict__ A, const unsigned short* __restrict__ Bt,
    const float* __restrict__ bias, const int* __restrict__ tok_of,
    const int* __restrict__ count,
    unsigned short* __restrict__ outH, unsigned short* __restrict__ outY,
    unsigned short* __restrict__ outY1,
    const float* __restrict__ W2src, unsigned short* __restrict__ w2tdst,
    const float* __restrict__ Bf32)
{
  __shared__ alignas(16) unsigned short smem[BM*64 + BN*64];   // 48KB, both roles
  constexpr int CT = NT / BN;          // ct values (16 GEMM1, 4 GEMM2)

  int by, ct, ks;
  if constexpr (TRW2 != 0){
    by = blockIdx.y;
    if (by >= NRB128){
      // ---- W2 transpose role: one 128x128 tile, 512 threads ----
      const int bid = (by - NRB128) * gridDim.x + blockIdx.x;    // 0..2047
      const int eT = bid >> 8, rem = bid & 255;
      const int R = DFFN, C = DIMD;         // W2: [4096][1024] -> w2t [1024][4096]
      const float* I = W2src + (size_t)eT * R * C;
      unsigned short* O = w2tdst + (size_t)eT * R * C;
      const int r0 = (rem >> 3) * 128, c0 = (rem & 7) * 128;     // 32 x 8 tiles
      unsigned short* tile = smem;          // 32KB of the 48KB block
      const int tid = threadIdx.x;
      const int qw = tid & 31, rw = tid >> 5;   // rw 0..15
      #pragma unroll
      for (int it = 0; it < 8; ++it){
        const int r = it * 16 + rw;
        const float4 v = *(const float4*)(I + (size_t)(r0 + r) * C + c0 + qw * 4);
        ushort4 o;
        o.x = f2bf(v.x); o.y = f2bf(v.y); o.z = f2bf(v.z); o.w = f2bf(v.w);
        const int slot = qw ^ ((r >> 2) & 31);
        *(ushort4*)&tile[r * 128 + slot * 4] = o;
      }
      __syncthreads();
      const int p = tid & 31, cb = tid >> 5;    // cb 0..15
      #pragma unroll
      for (int it = 0; it < 2; ++it){
        const int cg = cb * 2 + it;             // 0..31
        const int sl = (cg ^ p) * 4;
        const ushort4 a0 = *(const ushort4*)&tile[(4*p + 0) * 128 + sl];
        const ushort4 a1 = *(const ushort4*)&tile[(4*p + 1) * 128 + sl];
        const ushort4 a2 = *(const ushort4*)&tile[(4*p + 2) * 128 + sl];
        const ushort4 a3 = *(const ushort4*)&tile[(4*p + 3) * 128 + sl];
        ushort4 o;
        o.x = a0.x; o.y = a1.x; o.z = a2.x; o.w = a3.x;
        *(ushort4*)(O + (size_t)(c0 + 4*cg + 0) * R + r0 + 4*p) = o;
        o.x = a0.y; o.y = a1.y; o.z = a2.y; o.w = a3.y;
        *(ushort4*)(O + (size_t)(c0 + 4*cg + 1) * R + r0 + 4*p) = o;
        o.x = a0.z; o.y = a1.z; o.z = a2.z; o.w = a3.z;
        *(ushort4*)(O + (size_t)(c0 + 4*cg + 2) * R + r0 + 4*p) = o;
        o.x = a0.w; o.y = a1.w; o.z = a2.w; o.w = a3.w;
        *(ushort4*)(O + (size_t)(c0 + 4*cg + 3) * R + r0 + 4*p) = o;
      }
      return;
    }
    // GEMM1 role: expert-chunk XCD mapping. g in [0, 1152), hw XCD = g%8 = by/9.
    const int g = blockIdx.x + (int)gridDim.x * by;
    by = 9 * (g & 7) + ((g % 72) >> 3);
    ct = g / 72;
    ks = 0;
  } else {
    // GEMM2 role: 1D grid CT*NRB128*KSLICES (=576), expert-chunk XCD mapping.
    static_assert(CT * KSLICES == 8, "GEMM2 map assumes 8 blocks per rowblock");
    const int g = blockIdx.x;
    const int xx = g & 7;
    const int w  = g >> 3;            // [0, 72)
    by = 9 * xx + (w % 9);
    const int cw = w / 9;             // [0, 8)
    ct = cw % CT;
    ks = cw / CT;
  }

  // ---- GEMM role ----
  int e = -1, b0 = 0;
  #pragma unroll
  for (int q = 0; q < NEXP; ++q){
    const int nb = (count[q] + 127) >> 7;
    if (e < 0){ if (by < b0 + nb) e = q; else b0 += nb; }
  }
  if (e < 0) return;
  constexpr int KSL = KD / KSLICES;     // K elements per slice (multiple of 64)
  const int kbase = ks * KSL;
  const int row0 = by * 128;        // global padded slot row (pad-contiguous layout)
  constexpr int T   = WAVES * 64;   // threads
  constexpr int RA  = BM*8 / T;     // A staging rounds
  constexpr int RB  = BN*8 / T;     // B staging rounds (bf16 path)
  constexpr int WN  = BN / 64;      // wave-columns (64-wide)
  constexpr int WM  = WAVES / WN;   // wave-rows
  constexpr int MR  = BM / WM / 16; // 16-row fragment repeats per wave
  unsigned short* sA = smem;
  unsigned short* sB = smem + BM*64;
  const int tid = threadIdx.x, wid = tid >> 6, lane = tid & 63;

  // staging: slot s covers row s>>3, global chunk (s&7)^(row&7)
  const unsigned short* aptr[RA];
  #pragma unroll
  for (int i = 0; i < RA; ++i){
    const int s = i*T + tid;
    const int row = s >> 3;
    const int c = (s & 7) ^ (row & 7);
    size_t arow;
    if (MODE == 1) arow = (size_t)tok_of[row0 + row] * KD;
    else           arow = (size_t)(row0 + row) * KD;
    aptr[i] = A + arow + kbase + c*8;
  }
  const unsigned short* bptr[RB];
  if constexpr (BF32 == 0){
    #pragma unroll
    for (int i = 0; i < RB; ++i){
      const int s = i*T + tid;
      const int row = s >> 3;
      const int c = (s & 7) ^ (row & 7);
      bptr[i] = Bt + ((size_t)e*NT + ct*BN + row) * KD + kbase + c*8;
    }
  }
  // fp32 B source (GEMM1): wave wid covers k-rows 8*wid..8*wid+7; lane covers
  // n-cols 4*lane..4*lane+3 of the 256-wide tile. 1KB contiguous per wave-load.
  const float* bfp = nullptr;
  if constexpr (BF32 != 0)
    bfp = Bf32 + ((size_t)e*KD + kbase + 8*wid) * NT + ct*BN + 4*lane;

  f32x4 acc[MR][4] = {};
  const int wr = wid / WN, wc = wid % WN;   // wave tile (MR*16) x 64

  int aoff[MR][2], boff[4][2];
  #pragma unroll
  for (int m = 0; m < MR; ++m){
    #pragma unroll
    for (int s = 0; s < 2; ++s){
      const int rowA = wr*(MR*16) + m*16 + (lane & 15);
      aoff[m][s] = rowA*64 + (((s*4) + (lane >> 4)) ^ (rowA & 7))*8;
    }
  }
  #pragma unroll
  for (int n = 0; n < 4; ++n){
    #pragma unroll
    for (int s = 0; s < 2; ++s){
      const int rowB = wc*64 + n*16 + (lane & 15);
      const int sg = (BF32 != 0) ? ((rowB ^ (rowB >> 2)) & 7) : (rowB & 7);
      boff[n][s] = rowB*64 + (((s*4) + (lane >> 4)) ^ sg)*8;
    }
  }

  for (int k0 = 0; k0 < KSL; k0 += 64){
    if constexpr (BF32 != 0){
      float4 bv[8];
      const float* bp = bfp + (size_t)k0 * NT;
      #pragma unroll
      for (int r = 0; r < 8; ++r) bv[r] = *(const float4*)(bp + (size_t)r * NT);
      #pragma unroll
      for (int i = 0; i < RA; ++i)
        gload_lds16(aptr[i] + k0, &sA[(i*T + tid - lane)*8]);
      #pragma unroll
      for (int j = 0; j < 4; ++j){
        bf16x8 col;
        #pragma unroll
        for (int r = 0; r < 8; ++r)
          col[r] = (short)f2bf(((const float*)&bv[r])[j]);
        const int n = 4*lane + j;
        const int sg = (n ^ (n >> 2)) & 7;
        *(bf16x8*)&sB[n*64 + (wid ^ sg)*8] = col;
      }
    } else {
      #pragma unroll
      for (int i = 0; i < RA; ++i)
        gload_lds16(aptr[i] + k0, &sA[(i*T + tid - lane)*8]);
      #pragma unroll
      for (int i = 0; i < RB; ++i)
        gload_lds16(bptr[i] + k0, &sB[(i*T + tid - lane)*8]);
    }
    __syncthreads();
    #pragma unroll
    for (int s = 0; s < 2; ++s){
      bf16x8 af[MR], bfr[4];
      #pragma unroll
      for (int m = 0; m < MR; ++m) af[m] = *(const bf16x8*)&sA[aoff[m][s]];
      #pragma unroll
      for (int n = 0; n < 4; ++n) bfr[n] = *(const bf16x8*)&sB[boff[n][s]];
      #pragma unroll
      for (int m = 0; m < MR; ++m)
        #pragma unroll
        for (int n = 0; n < 4; ++n)
          acc[m][n] = __builtin_amdgcn_mfma_f32_16x16x32_bf16(af[m], bfr[n], acc[m][n], 0, 0, 0);
    }
    __syncthreads();
  }

  const float* be = bias + (size_t)e * NT;
  unsigned short* outYs = (ks == 0) ? outY : outY1;
  #pragma unroll
  for (int m = 0; m < MR; ++m){
    #pragma unroll
    for (int n = 0; n < 4; ++n){
      #pragma unroll
      for (int j = 0; j < 4; ++j){
        const int rl = wr*(MR*16) + m*16 + ((lane >> 4) << 2) + j;  // C row = (l>>4)*4+j
        const int ng = ct*BN + wc*64 + n*16 + (lane & 15);          // C col = l&15
        const size_t orow = (size_t)(row0 + rl) * NT + ng;          // pad rows: harmless
        if (MODE == 1){
          const float u = acc[m][n][j] + be[ng];
          // tanh-form GELU (|diff from exact| <~3e-3, << bf16 rounding of Hs)
          float y = 0.7978845608028654f * (u + 0.044715f * u * u * u);
          y = fminf(fmaxf(y, -15.f), 15.f);
          const float ex = __expf(2.f * y);
          const float th = (ex - 1.f) / (ex + 1.f);
          outH[orow] = f2bf(0.5f * u * (1.f + th));
        } else {
          outYs[orow] = f2bf(acc[m][n][j] + ((ks == 0) ? be[ng] : 0.f));
        }
      }
    }
  }
}

// ---------------- combine top-2 (sum bf16 split-K partials) + LayerNorm ----------------
__global__ __launch_bounds__(256) void k_combine_ln(
    const unsigned short* __restrict__ Ys0, const unsigned short* __restrict__ Ys1,
    const int* __restrict__ slot_of,
    const float* __restrict__ topw, const float* __restrict__ gamma,
    const float* __restrict__ beta, float* __restrict__ out)
{
  const int t = blockIdx.x;
  const int g0 = slot_of[t*2], g1 = slot_of[t*2+1];
  const float w0 = topw[t*2], w1 = topw[t*2+1];
  const int c = threadIdx.x;
  const ushort4 a0 = *(const ushort4*)(Ys0 + (size_t)g0*DIMD + c*4);
  const ushort4 a1 = *(const ushort4*)(Ys1 + (size_t)g0*DIMD + c*4);
  const ushort4 b0 = *(const ushort4*)(Ys0 + (size_t)g1*DIMD + c*4);
  const ushort4 b1 = *(const ushort4*)(Ys1 + (size_t)g1*DIMD + c*4);
  float4 v;
  v.x = w0*(bf2f(a0.x)+bf2f(a1.x)) + w1*(bf2f(b0.x)+bf2f(b1.x));
  v.y = w0*(bf2f(a0.y)+bf2f(a1.y)) + w1*(bf2f(b0.y)+bf2f(b1.y));
  v.z = w0*(bf2f(a0.z)+bf2f(a1.z)) + w1*(bf2f(b0.z)+bf2f(b1.z));
  v.w = w0*(bf2f(a0.w)+bf2f(a1.w)) + w1*(bf2f(b0.w)+bf2f(b1.w));
  float s  = v.x + v.y + v.z + v.w;
  float ss = v.x*v.x + v.y*v.y + v.z*v.z + v.w*v.w;
  #pragma unroll
  for (int o = 32; o > 0; o >>= 1){ s += __shfl_xor(s, o); ss += __shfl_xor(ss, o); }
  __shared__ float red[8];
  const int wid = threadIdx.x >> 6, lane = threadIdx.x & 63;
  if (lane == 0){ red[wid] = s; red[4 + wid] = ss; }
  __syncthreads();
  const float S  = red[0] + red[1] + red[2] + red[3];
  const float SS = red[4] + red[5] + red[6] + red[7];
  const float mu  = S * (1.f/DIMD);
  const float var = SS * (1.f/DIMD) - mu*mu;
  const float inv = rsqrtf(var + 1e-5f);
  const float4 gm = *(const float4*)(gamma + c*4);
  const float4 bt = *(const float4*)(beta + c*4);
  float4 o;
  o.x = (v.x - mu)*inv*gm.x + bt.x;
  o.y = (v.y - mu)*inv*gm.y + bt.y;
  o.z = (v.z - mu)*inv*gm.z + bt.z;
  o.w = (v.w - mu)*inv*gm.w + bt.w;
  *(float4*)(out + (size_t)t*DIMD + c*4) = o;
}

extern "C" void kernel_launch(void* const* d_in, const int* in_sizes, int n_in,
                              void* d_out, int out_size, void* d_ws, size_t ws_size,
                              hipStream_t stream)
{
  const float* x     = (const float*)d_in[0];
  const float* Wg    = (const float*)d_in[1];
  const float* bg    = (const float*)d_in[2];
  const float* W1    = (const float*)d_in[3];
  const float* b1    = (const float*)d_in[4];
  const float* W2    = (const float*)d_in[5];
  const float* b2    = (const float*)d_in[6];
  const float* gamma = (const float*)d_in[7];
  const float* beta  = (const float*)d_in[8];
  float* out = (float*)d_out;

  char* ws = (char*)d_ws;
  size_t off = 0;
  auto alloc = [&](size_t b){ char* p = ws + off; off += (b + 255) & ~(size_t)255; return p; };
  unsigned short* xb  = (unsigned short*)alloc((size_t)TOK*DIMD*2);
  unsigned short* Ys0b = (unsigned short*)alloc((size_t)NSLOT*DIMD*2);   // split-K partials
  unsigned short* Ys1b = (unsigned short*)alloc((size_t)NSLOT*DIMD*2);
  unsigned short* w2t = (unsigned short*)alloc((size_t)NEXP*DIMD*DFFN*2);
  unsigned short* Hs  = (unsigned short*)alloc((size_t)NSLOT*DFFN*2);
  int*   topidx  = (int*)alloc(TOK*2*4);
  float* topw    = (float*)alloc(TOK*2*4);
  int*   pos     = (int*)alloc(TOK*2*4);
  int*   slot_of = (int*)alloc(TOK*2*4);
  int*   tok_of  = (int*)alloc(NSLOT*4);
  int*   count   = (int*)alloc(256);

  (void)hipMemsetAsync(count, 0, NEXP*sizeof(int), stream);
  (void)hipMemsetAsync(tok_of, 0, NSLOT*sizeof(int), stream);  // pad rows -> token 0
  // Dispatch 1: gating only (W1 transpose eliminated — R13/R14).
  k_gate<<<TOK/4, 256, 0, stream>>>(x, Wg, bg, topidx, topw, pos, count, xb);
  k_scatter<<<TOK/256, 256, 0, stream>>>(topidx, pos, count, slot_of, tok_of);
  // GEMM1 (by<72, expert-chunk XCD map, B from fp32 W1, conflict-free sigma) +
  // W2 transpose (by 72..199), one launch.
  k_gemm<DIMD, 1, DFFN, 1, 8, 128, 256, 3, 1, 1><<<dim3(DFFN/256, NRB128 + 128), 512, 0, stream>>>(
      xb, nullptr, b1, tok_of, count, Hs, nullptr, nullptr, W2, w2t, W1);
  // GEMM2: 1D grid 576, expert-chunk XCD map (R12).
  k_gemm<DFFN, 2, DIMD, 2, 8, 128, 256, 4, 0, 0><<<dim3((DIMD/256)*NRB128*2), 512, 0, stream>>>(
      Hs, w2t, b2, tok_of, count, nullptr, Ys0b, Ys1b, nullptr, nullptr, nullptr);
  k_combine_ln<<<TOK, 256, 0, stream>>>(Ys0b, Ys1b, slot_of, topw, gamma, beta, out);
}

// Round 15
// 394.682 us; speedup vs baseline: 1.0506x; 1.0429x over previous
//
#include <hip/hip_runtime.h>
#include <hip/hip_bf16.h>

#define TOK  4096
#define DIMD 1024
#define NEXP 8
#define DFFN 4096
#define NSLOT   (TOK*2 + NEXP*128)       /* 9216 padded slots (128-aligned bases) */
#define NRB128  ((TOK*2)/128 + NEXP)     /* 72 worst-case 128-rowblocks */

typedef __attribute__((ext_vector_type(8))) short bf16x8;
typedef __attribute__((ext_vector_type(4))) float f32x4;

__device__ __forceinline__ unsigned short f2bf(float f){
  unsigned int u = __float_as_uint(f);
  unsigned int r = u + 0x7FFFu + ((u >> 16) & 1u);   // RNE (finite values only here)
  return (unsigned short)(r >> 16);
}

__device__ __forceinline__ float bf2f(unsigned short h){
  unsigned int u = ((unsigned int)h) << 16;
  return __uint_as_float(u);
}

__device__ __forceinline__ void gload_lds16(const void* g, void* l){
  __builtin_amdgcn_global_load_lds(
      (const __attribute__((address_space(1))) unsigned int*)g,
      (__attribute__((address_space(3))) unsigned int*)l, 16, 0, 0);
}

// ---- fused: W1 transpose (blocks 0..2047, LDS 128x128 tiles) + gating
// (blocks 2048..3071). Splitting costs ~6-9us (R2/R6/R10, 3x confirmed).
// Eliminating the transpose via fp32-B reg-staging in GEMM1 (R13/R14) regressed
// ~17us: reg-staging breaks the async gload_lds pipeline (VALUBusy 10->33%) and
// doubles B fetch. This transpose runs ~1.4 TB/s across 6 structural variants
// (VALUBusy 6%, 0 conflicts, clean coalescing) — treated as structural.
__global__ __launch_bounds__(256) void k_gate_trw1(
    const float* __restrict__ x, const float* __restrict__ Wg,
    const float* __restrict__ bg, int* __restrict__ topidx,
    float* __restrict__ topw, int* __restrict__ pos, int* __restrict__ count,
    unsigned short* __restrict__ xb,
    const float* __restrict__ W1, unsigned short* __restrict__ w1t)
{
  if (blockIdx.x < 2048){
    const int bid = blockIdx.x;
    const int e = bid >> 8, rem = bid & 255;
    const int R = DIMD, C = DFFN;         // W1: [1024][4096] -> w1t [4096][1024]
    const float* I = W1 + (size_t)e * R * C;
    unsigned short* O = w1t + (size_t)e * R * C;
    const int r0 = (rem >> 5) * 128, c0 = (rem & 31) * 128;  // 8 x 32 tiles
    __shared__ alignas(16) unsigned short tile[128*128];     // 32KB, swizzled slots
    const int tid = threadIdx.x;
    const int qw = tid & 31;              // col-group: cols 4qw..4qw+3
    const int rw = tid >> 5;              // row-within-octet
    #pragma unroll
    for (int it = 0; it < 16; ++it){
      const int r = it * 8 + rw;
      const float4 v = *(const float4*)(I + (size_t)(r0 + r) * C + c0 + qw * 4);
      ushort4 o;
      o.x = f2bf(v.x); o.y = f2bf(v.y); o.z = f2bf(v.z); o.w = f2bf(v.w);
      const int slot = qw ^ ((r >> 2) & 31);
      *(ushort4*)&tile[r * 128 + slot * 4] = o;
    }
    __syncthreads();
    const int p  = tid & 31;              // row-group: rows 4p..4p+3
    const int cb = tid >> 5;              // 0..7
    #pragma unroll
    for (int it = 0; it < 4; ++it){
      const int cg = cb * 4 + it;         // out col-group 0..31
      const int sl = (cg ^ p) * 4;
      const ushort4 a0 = *(const ushort4*)&tile[(4*p + 0) * 128 + sl];
      const ushort4 a1 = *(const ushort4*)&tile[(4*p + 1) * 128 + sl];
      const ushort4 a2 = *(const ushort4*)&tile[(4*p + 2) * 128 + sl];
      const ushort4 a3 = *(const ushort4*)&tile[(4*p + 3) * 128 + sl];
      ushort4 o;
      o.x = a0.x; o.y = a1.x; o.z = a2.x; o.w = a3.x;
      *(ushort4*)(O + (size_t)(c0 + 4*cg + 0) * R + r0 + 4*p) = o;
      o.x = a0.y; o.y = a1.y; o.z = a2.y; o.w = a3.y;
      *(ushort4*)(O + (size_t)(c0 + 4*cg + 1) * R + r0 + 4*p) = o;
      o.x = a0.z; o.y = a1.z; o.z = a2.z; o.w = a3.z;
      *(ushort4*)(O + (size_t)(c0 + 4*cg + 2) * R + r0 + 4*p) = o;
      o.x = a0.w; o.y = a1.w; o.z = a2.w; o.w = a3.w;
      *(ushort4*)(O + (size_t)(c0 + 4*cg + 3) * R + r0 + 4*p) = o;
    }
    return;
  }
  // ---------------- gating path ----------------
  const int gb = blockIdx.x - 2048;
  const int wid = threadIdx.x >> 6, lane = threadIdx.x & 63;
  const int t = gb * 4 + wid;
  const float* xr = x + (size_t)t * DIMD;
  unsigned short* xbr = xb + (size_t)t * DIMD;
  float acc[NEXP] = {0.f,0.f,0.f,0.f,0.f,0.f,0.f,0.f};
  #pragma unroll
  for (int j = 0; j < DIMD/64; ++j){
    const int d = j*64 + lane;
    const float xv = xr[d];
    xbr[d] = f2bf(xv);                       // fused bf16 conversion
    const float4 wa = *(const float4*)(Wg + (size_t)d*NEXP);
    const float4 wb = *(const float4*)(Wg + (size_t)d*NEXP + 4);
    acc[0] += xv*wa.x; acc[1] += xv*wa.y; acc[2] += xv*wa.z; acc[3] += xv*wa.w;
    acc[4] += xv*wb.x; acc[5] += xv*wb.y; acc[6] += xv*wb.z; acc[7] += xv*wb.w;
  }
  #pragma unroll
  for (int e = 0; e < NEXP; ++e){
    float v = acc[e];
    #pragma unroll
    for (int o = 32; o > 0; o >>= 1) v += __shfl_xor(v, o);
    acc[e] = v;
  }
  if (lane == 0){
    float lg[NEXP], m = -1e30f;
    #pragma unroll
    for (int e = 0; e < NEXP; ++e){ lg[e] = acc[e] + bg[e]; m = fmaxf(m, lg[e]); }
    float p[NEXP], S = 0.f;
    #pragma unroll
    for (int e = 0; e < NEXP; ++e){ p[e] = expf(lg[e] - m); S += p[e]; }
    int e0 = 0;
    #pragma unroll
    for (int e = 1; e < NEXP; ++e) if (p[e] > p[e0]) e0 = e;
    int e1 = (e0 == 0) ? 1 : 0;
    #pragma unroll
    for (int e = 0; e < NEXP; ++e){
      if (e == e0 || e == e1) continue;
      if (p[e] > p[e1]) e1 = e;
    }
    const float denom = p[e0] + p[e1] + 1e-8f * S;   // == top_sum + EPS, scaled by S
    const float w0 = p[e0] / denom, w1 = p[e1] / denom;
    const int p0 = atomicAdd(&count[e0], 1);
    const int p1 = atomicAdd(&count[e1], 1);
    topidx[t*2] = e0; topidx[t*2+1] = e1;
    topw[t*2] = w0;   topw[t*2+1] = w1;
    pos[t*2] = p0;    pos[t*2+1] = p1;
  }
}

// scatter with inline prefix-scan of count (128-aligned padded bases)
__global__ __launch_bounds__(256) void k_scatter(
    const int* __restrict__ topidx, const int* __restrict__ pos,
    const int* __restrict__ count, int* __restrict__ slot_of, int* __restrict__ tok_of)
{
  int basee[NEXP]; int bacc = 0;
  #pragma unroll
  for (int q = 0; q < NEXP; ++q){
    basee[q] = bacc << 7;
    bacc += (count[q] + 127) >> 7;
  }
  const int t = blockIdx.x * 256 + threadIdx.x;
  #pragma unroll
  for (int k = 0; k < 2; ++k){
    const int e = topidx[t*2+k];
    const int g = basee[e] + pos[t*2+k];
    slot_of[t*2+k] = g;
    tok_of[g] = t;
  }
}

// ---------- MFMA GEMM: BM x BN tile, BK=64, 8 waves, single-buffer (R2-proven) ----------
// Expert-chunk XCD mapping (validated R7/R8/R9/R12 via FETCH A/B: XCD ~ hw_id%8).
// 72 = 8 XCDs x 9 rowblocks; XCD x owns by in [9x,9x+9) with ALL (ct,ks) -> every
// block sharing an A-panel sits on ONE XCD; A fetched ~once, B streamed ~1x.
// GEMM1 (TRW2=1, 2D grid): g = bx + 16*by < 1152 -> by=9*(g&7)+(g%72)/8, ct=g/72.
// GEMM2 (TRW2=0, 1D grid 576): x=g&7, w=g>>3, by=9x+w%9, ct=(w/9)%CT, ks=(w/9)/CT.
// TRW2=1 also fuses the W2 transpose as extra blocks (by >= NRB128) — R7.
// MODE 1: A gathered via tok_of, epilogue bias+GELU -> bf16 outH
// MODE 2: A slot-contiguous, split-K, bias(ks==0) -> Ys0/Ys1
template<int KD, int KSLICES, int NT, int MODE, int WAVES, int BM, int BN, int MINW, int TRW2>
__global__ __launch_bounds__(WAVES*64, MINW) void k_gemm(
    const unsigned short* __restrict__ A, const unsigned short* __restrict__ Bt,
    const float* __restrict__ bias, const int* __restrict__ tok_of,
    const int* __restrict__ count,
    unsigned short* __restrict__ outH, unsigned short* __restrict__ outY,
    unsigned short* __restrict__ outY1,
    const float* __restrict__ W2src, unsigned short* __restrict__ w2tdst)
{
  __shared__ alignas(16) unsigned short smem[BM*64 + BN*64];   // 48KB, both roles
  constexpr int CT = NT / BN;          // ct values (16 GEMM1, 4 GEMM2)

  int by, ct, ks;
  if constexpr (TRW2 != 0){
    by = blockIdx.y;
    if (by >= NRB128){
      // ---- W2 transpose role: one 128x128 tile, 512 threads ----
      const int bid = (by - NRB128) * gridDim.x + blockIdx.x;    // 0..2047
      const int eT = bid >> 8, rem = bid & 255;
      const int R = DFFN, C = DIMD;         // W2: [4096][1024] -> w2t [1024][4096]
      const float* I = W2src + (size_t)eT * R * C;
      unsigned short* O = w2tdst + (size_t)eT * R * C;
      const int r0 = (rem >> 3) * 128, c0 = (rem & 7) * 128;     // 32 x 8 tiles
      unsigned short* tile = smem;          // 32KB of the 48KB block
      const int tid = threadIdx.x;
      const int qw = tid & 31, rw = tid >> 5;   // rw 0..15
      #pragma unroll
      for (int it = 0; it < 8; ++it){
        const int r = it * 16 + rw;
        const float4 v = *(const float4*)(I + (size_t)(r0 + r) * C + c0 + qw * 4);
        ushort4 o;
        o.x = f2bf(v.x); o.y = f2bf(v.y); o.z = f2bf(v.z); o.w = f2bf(v.w);
        const int slot = qw ^ ((r >> 2) & 31);
        *(ushort4*)&tile[r * 128 + slot * 4] = o;
      }
      __syncthreads();
      const int p = tid & 31, cb = tid >> 5;    // cb 0..15
      #pragma unroll
      for (int it = 0; it < 2; ++it){
        const int cg = cb * 2 + it;             // 0..31
        const int sl = (cg ^ p) * 4;
        const ushort4 a0 = *(const ushort4*)&tile[(4*p + 0) * 128 + sl];
        const ushort4 a1 = *(const ushort4*)&tile[(4*p + 1) * 128 + sl];
        const ushort4 a2 = *(const ushort4*)&tile[(4*p + 2) * 128 + sl];
        const ushort4 a3 = *(const ushort4*)&tile[(4*p + 3) * 128 + sl];
        ushort4 o;
        o.x = a0.x; o.y = a1.x; o.z = a2.x; o.w = a3.x;
        *(ushort4*)(O + (size_t)(c0 + 4*cg + 0) * R + r0 + 4*p) = o;
        o.x = a0.y; o.y = a1.y; o.z = a2.y; o.w = a3.y;
        *(ushort4*)(O + (size_t)(c0 + 4*cg + 1) * R + r0 + 4*p) = o;
        o.x = a0.z; o.y = a1.z; o.z = a2.z; o.w = a3.z;
        *(ushort4*)(O + (size_t)(c0 + 4*cg + 2) * R + r0 + 4*p) = o;
        o.x = a0.w; o.y = a1.w; o.z = a2.w; o.w = a3.w;
        *(ushort4*)(O + (size_t)(c0 + 4*cg + 3) * R + r0 + 4*p) = o;
      }
      return;
    }
    // GEMM1 role: expert-chunk XCD mapping. g in [0, 1152), hw XCD = g%8 = by/9.
    const int g = blockIdx.x + (int)gridDim.x * by;
    by = 9 * (g & 7) + ((g % 72) >> 3);
    ct = g / 72;
    ks = 0;
  } else {
    // GEMM2 role: 1D grid CT*NRB128*KSLICES (=576), expert-chunk XCD mapping.
    static_assert(CT * KSLICES == 8, "GEMM2 map assumes 8 blocks per rowblock");
    const int g = blockIdx.x;
    const int xx = g & 7;
    const int w  = g >> 3;            // [0, 72)
    by = 9 * xx + (w % 9);
    const int cw = w / 9;             // [0, 8)
    ct = cw % CT;
    ks = cw / CT;
  }

  // ---- GEMM role ----
  int e = -1, b0 = 0;
  #pragma unroll
  for (int q = 0; q < NEXP; ++q){
    const int nb = (count[q] + 127) >> 7;
    if (e < 0){ if (by < b0 + nb) e = q; else b0 += nb; }
  }
  if (e < 0) return;
  constexpr int KSL = KD / KSLICES;     // K elements per slice (multiple of 64)
  const int kbase = ks * KSL;
  const int row0 = by * 128;        // global padded slot row (pad-contiguous layout)
  constexpr int T   = WAVES * 64;   // threads
  constexpr int RA  = BM*8 / T;     // A staging rounds
  constexpr int RB  = BN*8 / T;     // B staging rounds
  constexpr int WN  = BN / 64;      // wave-columns (64-wide)
  constexpr int WM  = WAVES / WN;   // wave-rows
  constexpr int MR  = BM / WM / 16; // 16-row fragment repeats per wave
  unsigned short* sA = smem;
  unsigned short* sB = smem + BM*64;
  const int tid = threadIdx.x, wid = tid >> 6, lane = tid & 63;

  // staging: slot s covers row s>>3, global chunk (s&7)^(row&7)
  const unsigned short* aptr[RA];
  #pragma unroll
  for (int i = 0; i < RA; ++i){
    const int s = i*T + tid;
    const int row = s >> 3;
    const int c = (s & 7) ^ (row & 7);
    size_t arow;
    if (MODE == 1) arow = (size_t)tok_of[row0 + row] * KD;
    else           arow = (size_t)(row0 + row) * KD;
    aptr[i] = A + arow + kbase + c*8;
  }
  const unsigned short* bptr[RB];
  #pragma unroll
  for (int i = 0; i < RB; ++i){
    const int s = i*T + tid;
    const int row = s >> 3;
    const int c = (s & 7) ^ (row & 7);
    bptr[i] = Bt + ((size_t)e*NT + ct*BN + row) * KD + kbase + c*8;
  }

  f32x4 acc[MR][4] = {};
  const int wr = wid / WN, wc = wid % WN;   // wave tile (MR*16) x 64

  int aoff[MR][2], boff[4][2];
  #pragma unroll
  for (int m = 0; m < MR; ++m){
    #pragma unroll
    for (int s = 0; s < 2; ++s){
      const int rowA = wr*(MR*16) + m*16 + (lane & 15);
      aoff[m][s] = rowA*64 + (((s*4) + (lane >> 4)) ^ (rowA & 7))*8;
    }
  }
  #pragma unroll
  for (int n = 0; n < 4; ++n){
    #pragma unroll
    for (int s = 0; s < 2; ++s){
      const int rowB = wc*64 + n*16 + (lane & 15);
      boff[n][s] = rowB*64 + (((s*4) + (lane >> 4)) ^ (rowB & 7))*8;
    }
  }

  for (int k0 = 0; k0 < KSL; k0 += 64){
    #pragma unroll
    for (int i = 0; i < RA; ++i)
      gload_lds16(aptr[i] + k0, &sA[(i*T + tid - lane)*8]);
    #pragma unroll
    for (int i = 0; i < RB; ++i)
      gload_lds16(bptr[i] + k0, &sB[(i*T + tid - lane)*8]);
    __syncthreads();
    #pragma unroll
    for (int s = 0; s < 2; ++s){
      bf16x8 af[MR], bfr[4];
      #pragma unroll
      for (int m = 0; m < MR; ++m) af[m] = *(const bf16x8*)&sA[aoff[m][s]];
      #pragma unroll
      for (int n = 0; n < 4; ++n) bfr[n] = *(const bf16x8*)&sB[boff[n][s]];
      #pragma unroll
      for (int m = 0; m < MR; ++m)
        #pragma unroll
        for (int n = 0; n < 4; ++n)
          acc[m][n] = __builtin_amdgcn_mfma_f32_16x16x32_bf16(af[m], bfr[n], acc[m][n], 0, 0, 0);
    }
    __syncthreads();
  }

  const float* be = bias + (size_t)e * NT;
  unsigned short* outYs = (ks == 0) ? outY : outY1;
  #pragma unroll
  for (int m = 0; m < MR; ++m){
    #pragma unroll
    for (int n = 0; n < 4; ++n){
      #pragma unroll
      for (int j = 0; j < 4; ++j){
        const int rl = wr*(MR*16) + m*16 + ((lane >> 4) << 2) + j;  // C row = (l>>4)*4+j
        const int ng = ct*BN + wc*64 + n*16 + (lane & 15);          // C col = l&15
        const size_t orow = (size_t)(row0 + rl) * NT + ng;          // pad rows: harmless
        if (MODE == 1){
          const float u = acc[m][n][j] + be[ng];
          // tanh-form GELU (|diff from exact| <~3e-3, << bf16 rounding of Hs)
          float y = 0.7978845608028654f * (u + 0.044715f * u * u * u);
          y = fminf(fmaxf(y, -15.f), 15.f);
          const float ex = __expf(2.f * y);
          const float th = (ex - 1.f) / (ex + 1.f);
          outH[orow] = f2bf(0.5f * u * (1.f + th));
        } else {
          outYs[orow] = f2bf(acc[m][n][j] + ((ks == 0) ? be[ng] : 0.f));
        }
      }
    }
  }
}

// ---------------- combine top-2 (sum bf16 split-K partials) + LayerNorm ----------------
__global__ __launch_bounds__(256) void k_combine_ln(
    const unsigned short* __restrict__ Ys0, const unsigned short* __restrict__ Ys1,
    const int* __restrict__ slot_of,
    const float* __restrict__ topw, const float* __restrict__ gamma,
    const float* __restrict__ beta, float* __restrict__ out)
{
  const int t = blockIdx.x;
  const int g0 = slot_of[t*2], g1 = slot_of[t*2+1];
  const float w0 = topw[t*2], w1 = topw[t*2+1];
  const int c = threadIdx.x;
  const ushort4 a0 = *(const ushort4*)(Ys0 + (size_t)g0*DIMD + c*4);
  const ushort4 a1 = *(const ushort4*)(Ys1 + (size_t)g0*DIMD + c*4);
  const ushort4 b0 = *(const ushort4*)(Ys0 + (size_t)g1*DIMD + c*4);
  const ushort4 b1 = *(const ushort4*)(Ys1 + (size_t)g1*DIMD + c*4);
  float4 v;
  v.x = w0*(bf2f(a0.x)+bf2f(a1.x)) + w1*(bf2f(b0.x)+bf2f(b1.x));
  v.y = w0*(bf2f(a0.y)+bf2f(a1.y)) + w1*(bf2f(b0.y)+bf2f(b1.y));
  v.z = w0*(bf2f(a0.z)+bf2f(a1.z)) + w1*(bf2f(b0.z)+bf2f(b1.z));
  v.w = w0*(bf2f(a0.w)+bf2f(a1.w)) + w1*(bf2f(b0.w)+bf2f(b1.w));
  float s  = v.x + v.y + v.z + v.w;
  float ss = v.x*v.x + v.y*v.y + v.z*v.z + v.w*v.w;
  #pragma unroll
  for (int o = 32; o > 0; o >>= 1){ s += __shfl_xor(s, o); ss += __shfl_xor(ss, o); }
  __shared__ float red[8];
  const int wid = threadIdx.x >> 6, lane = threadIdx.x & 63;
  if (lane == 0){ red[wid] = s; red[4 + wid] = ss; }
  __syncthreads();
  const float S  = red[0] + red[1] + red[2] + red[3];
  const float SS = red[4] + red[5] + red[6] + red[7];
  const float mu  = S * (1.f/DIMD);
  const float var = SS * (1.f/DIMD) - mu*mu;
  const float inv = rsqrtf(var + 1e-5f);
  const float4 gm = *(const float4*)(gamma + c*4);
  const float4 bt = *(const float4*)(beta + c*4);
  float4 o;
  o.x = (v.x - mu)*inv*gm.x + bt.x;
  o.y = (v.y - mu)*inv*gm.y + bt.y;
  o.z = (v.z - mu)*inv*gm.z + bt.z;
  o.w = (v.w - mu)*inv*gm.w + bt.w;
  *(float4*)(out + (size_t)t*DIMD + c*4) = o;
}

extern "C" void kernel_launch(void* const* d_in, const int* in_sizes, int n_in,
                              void* d_out, int out_size, void* d_ws, size_t ws_size,
                              hipStream_t stream)
{
  const float* x     = (const float*)d_in[0];
  const float* Wg    = (const float*)d_in[1];
  const float* bg    = (const float*)d_in[2];
  const float* W1    = (const float*)d_in[3];
  const float* b1    = (const float*)d_in[4];
  const float* W2    = (const float*)d_in[5];
  const float* b2    = (const float*)d_in[6];
  const float* gamma = (const float*)d_in[7];
  const float* beta  = (const float*)d_in[8];
  float* out = (float*)d_out;

  char* ws = (char*)d_ws;
  size_t off = 0;
  auto alloc = [&](size_t b){ char* p = ws + off; off += (b + 255) & ~(size_t)255; return p; };
  unsigned short* xb  = (unsigned short*)alloc((size_t)TOK*DIMD*2);
  unsigned short* w1t = (unsigned short*)alloc((size_t)NEXP*DFFN*DIMD*2);
  unsigned short* w2t = (unsigned short*)alloc((size_t)NEXP*DIMD*DFFN*2);
  unsigned short* Hs  = (unsigned short*)alloc((size_t)NSLOT*DFFN*2);
  int*   topidx  = (int*)alloc(TOK*2*4);
  float* topw    = (float*)alloc(TOK*2*4);
  int*   pos     = (int*)alloc(TOK*2*4);
  int*   slot_of = (int*)alloc(TOK*2*4);
  int*   tok_of  = (int*)alloc(NSLOT*4);
  int*   count   = (int*)alloc(256);
  // split-K bf16 partials alias w1t (dead after GEMM1): 2 x 18.9MB = 37.8MB <= 64MB region.
  // w1t is read ONLY by GEMM1 (stream-ordered complete before GEMM2 writes the partials).
  unsigned short* Ys0b = (unsigned short*)w1t;
  unsigned short* Ys1b = Ys0b + (size_t)NSLOT*DIMD;

  (void)hipMemsetAsync(count, 0, NEXP*sizeof(int), stream);
  (void)hipMemsetAsync(tok_of, 0, NSLOT*sizeof(int), stream);  // pad rows -> token 0
  // Dispatch 1: W1 transpose (2048 blocks) + gating (1024 blocks), fused.
  k_gate_trw1<<<3072, 256, 0, stream>>>(x, Wg, bg, topidx, topw, pos, count, xb, W1, w1t);
  k_scatter<<<TOK/256, 256, 0, stream>>>(topidx, pos, count, slot_of, tok_of);
  // GEMM1 (by<72, expert-chunk XCD map) + W2 transpose (by 72..199), one launch.
  k_gemm<DIMD, 1, DFFN, 1, 8, 128, 256, 4, 1><<<dim3(DFFN/256, NRB128 + 128), 512, 0, stream>>>(
      xb, w1t, b1, tok_of, count, Hs, nullptr, nullptr, W2, w2t);
  // GEMM2: 1D grid 576, expert-chunk XCD map.
  k_gemm<DFFN, 2, DIMD, 2, 8, 128, 256, 4, 0><<<dim3((DIMD/256)*NRB128*2), 512, 0, stream>>>(
      Hs, w2t, b2, tok_of, count, nullptr, Ys0b, Ys1b, nullptr, nullptr);
  k_combine_ln<<<TOK, 256, 0, stream>>>(Ys0b, Ys1b, slot_of, topw, gamma, beta, out);
}

// Round 16
// 394.620 us; speedup vs baseline: 1.0508x; 1.0002x over previous
//
#include <hip/hip_runtime.h>
#include <hip/hip_bf16.h>

#define TOK  4096
#define DIMD 1024
#define NEXP 8
#define DFFN 4096
#define NSLOT   (TOK*2 + NEXP*128)       /* 9216 padded slots (128-aligned bases) */
#define NRB128  ((TOK*2)/128 + NEXP)     /* 72 worst-case 128-rowblocks */

typedef __attribute__((ext_vector_type(8))) short bf16x8;
typedef __attribute__((ext_vector_type(4))) float f32x4;

__device__ __forceinline__ unsigned short f2bf(float f){
  unsigned int u = __float_as_uint(f);
  unsigned int r = u + 0x7FFFu + ((u >> 16) & 1u);   // RNE (finite values only here)
  return (unsigned short)(r >> 16);
}

__device__ __forceinline__ float bf2f(unsigned short h){
  unsigned int u = ((unsigned int)h) << 16;
  return __uint_as_float(u);
}

__device__ __forceinline__ void gload_lds16(const void* g, void* l){
  __builtin_amdgcn_global_load_lds(
      (const __attribute__((address_space(1))) unsigned int*)g,
      (__attribute__((address_space(3))) unsigned int*)l, 16, 0, 0);
}

// ---- fused: W1 transpose (blocks 0..2047, LDS 128x128 tiles) + gating
// (blocks 2048..3071). R16: replay counters show dur is INVARIANT to HBM read
// traffic (L3-warm replays = cold runs = 152us) -> latency-chain-bound, not BW.
// At VGPR=48 phase 1 serializes load->wait->cvt->ds_write x16. Last untried knob:
// __launch_bounds__(256,1) (register budget up to 512) + explicit 16-deep load
// batch so the allocator can keep all 16 loads in flight (~64 VGPR of payload).
__global__ __launch_bounds__(256, 1) void k_gate_trw1(
    const float* __restrict__ x, const float* __restrict__ Wg,
    const float* __restrict__ bg, int* __restrict__ topidx,
    float* __restrict__ topw, int* __restrict__ pos, int* __restrict__ count,
    unsigned short* __restrict__ xb,
    const float* __restrict__ W1, unsigned short* __restrict__ w1t)
{
  if (blockIdx.x < 2048){
    const int bid = blockIdx.x;
    const int e = bid >> 8, rem = bid & 255;
    const int R = DIMD, C = DFFN;         // W1: [1024][4096] -> w1t [4096][1024]
    const float* I = W1 + (size_t)e * R * C;
    unsigned short* O = w1t + (size_t)e * R * C;
    const int r0 = (rem >> 5) * 128, c0 = (rem & 31) * 128;  // 8 x 32 tiles
    __shared__ alignas(16) unsigned short tile[128*128];     // 32KB, swizzled slots
    const int tid = threadIdx.x;
    const int qw = tid & 31;              // col-group: cols 4qw..4qw+3
    const int rw = tid >> 5;              // row-within-octet
    float4 v[16];
    #pragma unroll
    for (int it = 0; it < 16; ++it){
      const int r = it * 8 + rw;
      v[it] = *(const float4*)(I + (size_t)(r0 + r) * C + c0 + qw * 4);
    }
    #pragma unroll
    for (int it = 0; it < 16; ++it){
      const int r = it * 8 + rw;
      ushort4 o;
      o.x = f2bf(v[it].x); o.y = f2bf(v[it].y); o.z = f2bf(v[it].z); o.w = f2bf(v[it].w);
      const int slot = qw ^ ((r >> 2) & 31);
      *(ushort4*)&tile[r * 128 + slot * 4] = o;
    }
    __syncthreads();
    const int p  = tid & 31;              // row-group: rows 4p..4p+3
    const int cb = tid >> 5;              // 0..7
    #pragma unroll
    for (int it = 0; it < 4; ++it){
      const int cg = cb * 4 + it;         // out col-group 0..31
      const int sl = (cg ^ p) * 4;
      const ushort4 a0 = *(const ushort4*)&tile[(4*p + 0) * 128 + sl];
      const ushort4 a1 = *(const ushort4*)&tile[(4*p + 1) * 128 + sl];
      const ushort4 a2 = *(const ushort4*)&tile[(4*p + 2) * 128 + sl];
      const ushort4 a3 = *(const ushort4*)&tile[(4*p + 3) * 128 + sl];
      ushort4 o;
      o.x = a0.x; o.y = a1.x; o.z = a2.x; o.w = a3.x;
      *(ushort4*)(O + (size_t)(c0 + 4*cg + 0) * R + r0 + 4*p) = o;
      o.x = a0.y; o.y = a1.y; o.z = a2.y; o.w = a3.y;
      *(ushort4*)(O + (size_t)(c0 + 4*cg + 1) * R + r0 + 4*p) = o;
      o.x = a0.z; o.y = a1.z; o.z = a2.z; o.w = a3.z;
      *(ushort4*)(O + (size_t)(c0 + 4*cg + 2) * R + r0 + 4*p) = o;
      o.x = a0.w; o.y = a1.w; o.z = a2.w; o.w = a3.w;
      *(ushort4*)(O + (size_t)(c0 + 4*cg + 3) * R + r0 + 4*p) = o;
    }
    return;
  }
  // ---------------- gating path ----------------
  const int gb = blockIdx.x - 2048;
  const int wid = threadIdx.x >> 6, lane = threadIdx.x & 63;
  const int t = gb * 4 + wid;
  const float* xr = x + (size_t)t * DIMD;
  unsigned short* xbr = xb + (size_t)t * DIMD;
  float acc[NEXP] = {0.f,0.f,0.f,0.f,0.f,0.f,0.f,0.f};
  #pragma unroll
  for (int j = 0; j < DIMD/64; ++j){
    const int d = j*64 + lane;
    const float xv = xr[d];
    xbr[d] = f2bf(xv);                       // fused bf16 conversion
    const float4 wa = *(const float4*)(Wg + (size_t)d*NEXP);
    const float4 wb = *(const float4*)(Wg + (size_t)d*NEXP + 4);
    acc[0] += xv*wa.x; acc[1] += xv*wa.y; acc[2] += xv*wa.z; acc[3] += xv*wa.w;
    acc[4] += xv*wb.x; acc[5] += xv*wb.y; acc[6] += xv*wb.z; acc[7] += xv*wb.w;
  }
  #pragma unroll
  for (int e = 0; e < NEXP; ++e){
    float v = acc[e];
    #pragma unroll
    for (int o = 32; o > 0; o >>= 1) v += __shfl_xor(v, o);
    acc[e] = v;
  }
  if (lane == 0){
    float lg[NEXP], m = -1e30f;
    #pragma unroll
    for (int e = 0; e < NEXP; ++e){ lg[e] = acc[e] + bg[e]; m = fmaxf(m, lg[e]); }
    float p[NEXP], S = 0.f;
    #pragma unroll
    for (int e = 0; e < NEXP; ++e){ p[e] = expf(lg[e] - m); S += p[e]; }
    int e0 = 0;
    #pragma unroll
    for (int e = 1; e < NEXP; ++e) if (p[e] > p[e0]) e0 = e;
    int e1 = (e0 == 0) ? 1 : 0;
    #pragma unroll
    for (int e = 0; e < NEXP; ++e){
      if (e == e0 || e == e1) continue;
      if (p[e] > p[e1]) e1 = e;
    }
    const float denom = p[e0] + p[e1] + 1e-8f * S;   // == top_sum + EPS, scaled by S
    const float w0 = p[e0] / denom, w1 = p[e1] / denom;
    const int p0 = atomicAdd(&count[e0], 1);
    const int p1 = atomicAdd(&count[e1], 1);
    topidx[t*2] = e0; topidx[t*2+1] = e1;
    topw[t*2] = w0;   topw[t*2+1] = w1;
    pos[t*2] = p0;    pos[t*2+1] = p1;
  }
}

// scatter with inline prefix-scan of count (128-aligned padded bases)
__global__ __launch_bounds__(256) void k_scatter(
    const int* __restrict__ topidx, const int* __restrict__ pos,
    const int* __restrict__ count, int* __restrict__ slot_of, int* __restrict__ tok_of)
{
  int basee[NEXP]; int bacc = 0;
  #pragma unroll
  for (int q = 0; q < NEXP; ++q){
    basee[q] = bacc << 7;
    bacc += (count[q] + 127) >> 7;
  }
  const int t = blockIdx.x * 256 + threadIdx.x;
  #pragma unroll
  for (int k = 0; k < 2; ++k){
    const int e = topidx[t*2+k];
    const int g = basee[e] + pos[t*2+k];
    slot_of[t*2+k] = g;
    tok_of[g] = t;
  }
}

// ---------- MFMA GEMM: BM x BN tile, BK=64, 8 waves, single-buffer (R2-proven) ----------
// Expert-chunk XCD mapping (validated R7/R8/R9/R12 via FETCH A/B: XCD ~ hw_id%8).
// 72 = 8 XCDs x 9 rowblocks; XCD x owns by in [9x,9x+9) with ALL (ct,ks) -> every
// block sharing an A-panel sits on ONE XCD; A fetched ~once, B streamed ~1x.
// GEMM1 (TRW2=1, 2D grid): g = bx + 16*by < 1152 -> by=9*(g&7)+(g%72)/8, ct=g/72.
// GEMM2 (TRW2=0, 1D grid 576): x=g&7, w=g>>3, by=9x+w%9, ct=(w/9)%CT, ks=(w/9)/CT.
// TRW2=1 also fuses the W2 transpose as extra blocks (by >= NRB128) — R7.
// MODE 1: A gathered via tok_of, epilogue bias+GELU -> bf16 outH
// MODE 2: A slot-contiguous, split-K, bias(ks==0) -> Ys0/Ys1
template<int KD, int KSLICES, int NT, int MODE, int WAVES, int BM, int BN, int MINW, int TRW2>
__global__ __launch_bounds__(WAVES*64, MINW) void k_gemm(
    const unsigned short* __restrict__ A, const unsigned short* __restrict__ Bt,
    const float* __restrict__ bias, const int* __restrict__ tok_of,
    const int* __restrict__ count,
    unsigned short* __restrict__ outH, unsigned short* __restrict__ outY,
    unsigned short* __restrict__ outY1,
    const float* __restrict__ W2src, unsigned short* __restrict__ w2tdst)
{
  __shared__ alignas(16) unsigned short smem[BM*64 + BN*64];   // 48KB, both roles
  constexpr int CT = NT / BN;          // ct values (16 GEMM1, 4 GEMM2)

  int by, ct, ks;
  if constexpr (TRW2 != 0){
    by = blockIdx.y;
    if (by >= NRB128){
      // ---- W2 transpose role: one 128x128 tile, 512 threads ----
      const int bid = (by - NRB128) * gridDim.x + blockIdx.x;    // 0..2047
      const int eT = bid >> 8, rem = bid & 255;
      const int R = DFFN, C = DIMD;         // W2: [4096][1024] -> w2t [1024][4096]
      const float* I = W2src + (size_t)eT * R * C;
      unsigned short* O = w2tdst + (size_t)eT * R * C;
      const int r0 = (rem >> 3) * 128, c0 = (rem & 7) * 128;     // 32 x 8 tiles
      unsigned short* tile = smem;          // 32KB of the 48KB block
      const int tid = threadIdx.x;
      const int qw = tid & 31, rw = tid >> 5;   // rw 0..15
      #pragma unroll
      for (int it = 0; it < 8; ++it){
        const int r = it * 16 + rw;
        const float4 v = *(const float4*)(I + (size_t)(r0 + r) * C + c0 + qw * 4);
        ushort4 o;
        o.x = f2bf(v.x); o.y = f2bf(v.y); o.z = f2bf(v.z); o.w = f2bf(v.w);
        const int slot = qw ^ ((r >> 2) & 31);
        *(ushort4*)&tile[r * 128 + slot * 4] = o;
      }
      __syncthreads();
      const int p = tid & 31, cb = tid >> 5;    // cb 0..15
      #pragma unroll
      for (int it = 0; it < 2; ++it){
        const int cg = cb * 2 + it;             // 0..31
        const int sl = (cg ^ p) * 4;
        const ushort4 a0 = *(const ushort4*)&tile[(4*p + 0) * 128 + sl];
        const ushort4 a1 = *(const ushort4*)&tile[(4*p + 1) * 128 + sl];
        const ushort4 a2 = *(const ushort4*)&tile[(4*p + 2) * 128 + sl];
        const ushort4 a3 = *(const ushort4*)&tile[(4*p + 3) * 128 + sl];
        ushort4 o;
        o.x = a0.x; o.y = a1.x; o.z = a2.x; o.w = a3.x;
        *(ushort4*)(O + (size_t)(c0 + 4*cg + 0) * R + r0 + 4*p) = o;
        o.x = a0.y; o.y = a1.y; o.z = a2.y; o.w = a3.y;
        *(ushort4*)(O + (size_t)(c0 + 4*cg + 1) * R + r0 + 4*p) = o;
        o.x = a0.z; o.y = a1.z; o.z = a2.z; o.w = a3.z;
        *(ushort4*)(O + (size_t)(c0 + 4*cg + 2) * R + r0 + 4*p) = o;
        o.x = a0.w; o.y = a1.w; o.z = a2.w; o.w = a3.w;
        *(ushort4*)(O + (size_t)(c0 + 4*cg + 3) * R + r0 + 4*p) = o;
      }
      return;
    }
    // GEMM1 role: expert-chunk XCD mapping. g in [0, 1152), hw XCD = g%8 = by/9.
    const int g = blockIdx.x + (int)gridDim.x * by;
    by = 9 * (g & 7) + ((g % 72) >> 3);
    ct = g / 72;
    ks = 0;
  } else {
    // GEMM2 role: 1D grid CT*NRB128*KSLICES (=576), expert-chunk XCD mapping.
    static_assert(CT * KSLICES == 8, "GEMM2 map assumes 8 blocks per rowblock");
    const int g = blockIdx.x;
    const int xx = g & 7;
    const int w  = g >> 3;            // [0, 72)
    by = 9 * xx + (w % 9);
    const int cw = w / 9;             // [0, 8)
    ct = cw % CT;
    ks = cw / CT;
  }

  // ---- GEMM role ----
  int e = -1, b0 = 0;
  #pragma unroll
  for (int q = 0; q < NEXP; ++q){
    const int nb = (count[q] + 127) >> 7;
    if (e < 0){ if (by < b0 + nb) e = q; else b0 += nb; }
  }
  if (e < 0) return;
  constexpr int KSL = KD / KSLICES;     // K elements per slice (multiple of 64)
  const int kbase = ks * KSL;
  const int row0 = by * 128;        // global padded slot row (pad-contiguous layout)
  constexpr int T   = WAVES * 64;   // threads
  constexpr int RA  = BM*8 / T;     // A staging rounds
  constexpr int RB  = BN*8 / T;     // B staging rounds
  constexpr int WN  = BN / 64;      // wave-columns (64-wide)
  constexpr int WM  = WAVES / WN;   // wave-rows
  constexpr int MR  = BM / WM / 16; // 16-row fragment repeats per wave
  unsigned short* sA = smem;
  unsigned short* sB = smem + BM*64;
  const int tid = threadIdx.x, wid = tid >> 6, lane = tid & 63;

  // staging: slot s covers row s>>3, global chunk (s&7)^(row&7)
  const unsigned short* aptr[RA];
  #pragma unroll
  for (int i = 0; i < RA; ++i){
    const int s = i*T + tid;
    const int row = s >> 3;
    const int c = (s & 7) ^ (row & 7);
    size_t arow;
    if (MODE == 1) arow = (size_t)tok_of[row0 + row] * KD;
    else           arow = (size_t)(row0 + row) * KD;
    aptr[i] = A + arow + kbase + c*8;
  }
  const unsigned short* bptr[RB];
  #pragma unroll
  for (int i = 0; i < RB; ++i){
    const int s = i*T + tid;
    const int row = s >> 3;
    const int c = (s & 7) ^ (row & 7);
    bptr[i] = Bt + ((size_t)e*NT + ct*BN + row) * KD + kbase + c*8;
  }

  f32x4 acc[MR][4] = {};
  const int wr = wid / WN, wc = wid % WN;   // wave tile (MR*16) x 64

  int aoff[MR][2], boff[4][2];
  #pragma unroll
  for (int m = 0; m < MR; ++m){
    #pragma unroll
    for (int s = 0; s < 2; ++s){
      const int rowA = wr*(MR*16) + m*16 + (lane & 15);
      aoff[m][s] = rowA*64 + (((s*4) + (lane >> 4)) ^ (rowA & 7))*8;
    }
  }
  #pragma unroll
  for (int n = 0; n < 4; ++n){
    #pragma unroll
    for (int s = 0; s < 2; ++s){
      const int rowB = wc*64 + n*16 + (lane & 15);
      boff[n][s] = rowB*64 + (((s*4) + (lane >> 4)) ^ (rowB & 7))*8;
    }
  }

  for (int k0 = 0; k0 < KSL; k0 += 64){
    #pragma unroll
    for (int i = 0; i < RA; ++i)
      gload_lds16(aptr[i] + k0, &sA[(i*T + tid - lane)*8]);
    #pragma unroll
    for (int i = 0; i < RB; ++i)
      gload_lds16(bptr[i] + k0, &sB[(i*T + tid - lane)*8]);
    __syncthreads();
    #pragma unroll
    for (int s = 0; s < 2; ++s){
      bf16x8 af[MR], bfr[4];
      #pragma unroll
      for (int m = 0; m < MR; ++m) af[m] = *(const bf16x8*)&sA[aoff[m][s]];
      #pragma unroll
      for (int n = 0; n < 4; ++n) bfr[n] = *(const bf16x8*)&sB[boff[n][s]];
      #pragma unroll
      for (int m = 0; m < MR; ++m)
        #pragma unroll
        for (int n = 0; n < 4; ++n)
          acc[m][n] = __builtin_amdgcn_mfma_f32_16x16x32_bf16(af[m], bfr[n], acc[m][n], 0, 0, 0);
    }
    __syncthreads();
  }

  const float* be = bias + (size_t)e * NT;
  unsigned short* outYs = (ks == 0) ? outY : outY1;
  #pragma unroll
  for (int m = 0; m < MR; ++m){
    #pragma unroll
    for (int n = 0; n < 4; ++n){
      #pragma unroll
      for (int j = 0; j < 4; ++j){
        const int rl = wr*(MR*16) + m*16 + ((lane >> 4) << 2) + j;  // C row = (l>>4)*4+j
        const int ng = ct*BN + wc*64 + n*16 + (lane & 15);          // C col = l&15
        const size_t orow = (size_t)(row0 + rl) * NT + ng;          // pad rows: harmless
        if (MODE == 1){
          const float u = acc[m][n][j] + be[ng];
          // tanh-form GELU (|diff from exact| <~3e-3, << bf16 rounding of Hs)
          float y = 0.7978845608028654f * (u + 0.044715f * u * u * u);
          y = fminf(fmaxf(y, -15.f), 15.f);
          const float ex = __expf(2.f * y);
          const float th = (ex - 1.f) / (ex + 1.f);
          outH[orow] = f2bf(0.5f * u * (1.f + th));
        } else {
          outYs[orow] = f2bf(acc[m][n][j] + ((ks == 0) ? be[ng] : 0.f));
        }
      }
    }
  }
}

// ---------------- combine top-2 (sum bf16 split-K partials) + LayerNorm ----------------
__global__ __launch_bounds__(256) void k_combine_ln(
    const unsigned short* __restrict__ Ys0, const unsigned short* __restrict__ Ys1,
    const int* __restrict__ slot_of,
    const float* __restrict__ topw, const float* __restrict__ gamma,
    const float* __restrict__ beta, float* __restrict__ out)
{
  const int t = blockIdx.x;
  const int g0 = slot_of[t*2], g1 = slot_of[t*2+1];
  const float w0 = topw[t*2], w1 = topw[t*2+1];
  const int c = threadIdx.x;
  const ushort4 a0 = *(const ushort4*)(Ys0 + (size_t)g0*DIMD + c*4);
  const ushort4 a1 = *(const ushort4*)(Ys1 + (size_t)g0*DIMD + c*4);
  const ushort4 b0 = *(const ushort4*)(Ys0 + (size_t)g1*DIMD + c*4);
  const ushort4 b1 = *(const ushort4*)(Ys1 + (size_t)g1*DIMD + c*4);
  float4 v;
  v.x = w0*(bf2f(a0.x)+bf2f(a1.x)) + w1*(bf2f(b0.x)+bf2f(b1.x));
  v.y = w0*(bf2f(a0.y)+bf2f(a1.y)) + w1*(bf2f(b0.y)+bf2f(b1.y));
  v.z = w0*(bf2f(a0.z)+bf2f(a1.z)) + w1*(bf2f(b0.z)+bf2f(b1.z));
  v.w = w0*(bf2f(a0.w)+bf2f(a1.w)) + w1*(bf2f(b0.w)+bf2f(b1.w));
  float s  = v.x + v.y + v.z + v.w;
  float ss = v.x*v.x + v.y*v.y + v.z*v.z + v.w*v.w;
  #pragma unroll
  for (int o = 32; o > 0; o >>= 1){ s += __shfl_xor(s, o); ss += __shfl_xor(ss, o); }
  __shared__ float red[8];
  const int wid = threadIdx.x >> 6, lane = threadIdx.x & 63;
  if (lane == 0){ red[wid] = s; red[4 + wid] = ss; }
  __syncthreads();
  const float S  = red[0] + red[1] + red[2] + red[3];
  const float SS = red[4] + red[5] + red[6] + red[7];
  const float mu  = S * (1.f/DIMD);
  const float var = SS * (1.f/DIMD) - mu*mu;
  const float inv = rsqrtf(var + 1e-5f);
  const float4 gm = *(const float4*)(gamma + c*4);
  const float4 bt = *(const float4*)(beta + c*4);
  float4 o;
  o.x = (v.x - mu)*inv*gm.x + bt.x;
  o.y = (v.y - mu)*inv*gm.y + bt.y;
  o.z = (v.z - mu)*inv*gm.z + bt.z;
  o.w = (v.w - mu)*inv*gm.w + bt.w;
  *(float4*)(out + (size_t)t*DIMD + c*4) = o;
}

extern "C" void kernel_launch(void* const* d_in, const int* in_sizes, int n_in,
                              void* d_out, int out_size, void* d_ws, size_t ws_size,
                              hipStream_t stream)
{
  const float* x     = (const float*)d_in[0];
  const float* Wg    = (const float*)d_in[1];
  const float* bg    = (const float*)d_in[2];
  const float* W1    = (const float*)d_in[3];
  const float* b1    = (const float*)d_in[4];
  const float* W2    = (const float*)d_in[5];
  const float* b2    = (const float*)d_in[6];
  const float* gamma = (const float*)d_in[7];
  const float* beta  = (const float*)d_in[8];
  float* out = (float*)d_out;

  char* ws = (char*)d_ws;
  size_t off = 0;
  auto alloc = [&](size_t b){ char* p = ws + off; off += (b + 255) & ~(size_t)255; return p; };
  unsigned short* xb  = (unsigned short*)alloc((size_t)TOK*DIMD*2);
  unsigned short* w1t = (unsigned short*)alloc((size_t)NEXP*DFFN*DIMD*2);
  unsigned short* w2t = (unsigned short*)alloc((size_t)NEXP*DIMD*DFFN*2);
  unsigned short* Hs  = (unsigned short*)alloc((size_t)NSLOT*DFFN*2);
  int*   topidx  = (int*)alloc(TOK*2*4);
  float* topw    = (float*)alloc(TOK*2*4);
  int*   pos     = (int*)alloc(TOK*2*4);
  int*   slot_of = (int*)alloc(TOK*2*4);
  int*   tok_of  = (int*)alloc(NSLOT*4);
  int*   count   = (int*)alloc(256);
  // split-K bf16 partials alias w1t (dead after GEMM1): 2 x 18.9MB = 37.8MB <= 64MB region.
  // w1t is read ONLY by GEMM1 (stream-ordered complete before GEMM2 writes the partials).
  unsigned short* Ys0b = (unsigned short*)w1t;
  unsigned short* Ys1b = Ys0b + (size_t)NSLOT*DIMD;

  (void)hipMemsetAsync(count, 0, NEXP*sizeof(int), stream);
  (void)hipMemsetAsync(tok_of, 0, NSLOT*sizeof(int), stream);  // pad rows -> token 0
  // Dispatch 1: W1 transpose (2048 blocks, 16-deep batch, relaxed regalloc) +
  // gating (1024 blocks), fused.
  k_gate_trw1<<<3072, 256, 0, stream>>>(x, Wg, bg, topidx, topw, pos, count, xb, W1, w1t);
  k_scatter<<<TOK/256, 256, 0, stream>>>(topidx, pos, count, slot_of, tok_of);
  // GEMM1 (by<72, expert-chunk XCD map) + W2 transpose (by 72..199), one launch.
  k_gemm<DIMD, 1, DFFN, 1, 8, 128, 256, 4, 1><<<dim3(DFFN/256, NRB128 + 128), 512, 0, stream>>>(
      xb, w1t, b1, tok_of, count, Hs, nullptr, nullptr, W2, w2t);
  // GEMM2: 1D grid 576, expert-chunk XCD map.
  k_gemm<DFFN, 2, DIMD, 2, 8, 128, 256, 4, 0><<<dim3((DIMD/256)*NRB128*2), 512, 0, stream>>>(
      Hs, w2t, b2, tok_of, count, nullptr, Ys0b, Ys1b, nullptr, nullptr);
  k_combine_ln<<<TOK, 256, 0, stream>>>(Ys0b, Ys1b, slot_of, topw, gamma, beta, out);
}

// Round 17
// 387.743 us; speedup vs baseline: 1.0694x; 1.0177x over previous
//
#include <hip/hip_runtime.h>
#include <hip/hip_bf16.h>

#define TOK  4096
#define DIMD 1024
#define NEXP 8
#define DFFN 4096
#define NSLOT   (TOK*2 + NEXP*128)       /* 9216 padded slots (128-aligned bases) */
#define NRB128  ((TOK*2)/128 + NEXP)     /* 72 worst-case 128-rowblocks */

typedef __attribute__((ext_vector_type(8))) short bf16x8;
typedef __attribute__((ext_vector_type(4))) float f32x4;

__device__ __forceinline__ unsigned short f2bf(float f){
  unsigned int u = __float_as_uint(f);
  unsigned int r = u + 0x7FFFu + ((u >> 16) & 1u);   // RNE (finite values only here)
  return (unsigned short)(r >> 16);
}

__device__ __forceinline__ float bf2f(unsigned short h){
  unsigned int u = ((unsigned int)h) << 16;
  return __uint_as_float(u);
}

__device__ __forceinline__ void gload_lds16(const void* g, void* l){
  __builtin_amdgcn_global_load_lds(
      (const __attribute__((address_space(1))) unsigned int*)g,
      (__attribute__((address_space(3))) unsigned int*)l, 16, 0, 0);
}

// ---- fused: W1 transpose (blocks 0..2047, LDS 128x128 tiles) + gating
// (blocks 2048..3071).
// R17: w1t layout changed to k-blocked [16 kb][4096 n][64 k] per expert.
// Evidence: replay passes (reads L3-absorbed, only 74MB writes to HBM) take the
// SAME 152us as cold -> 0.49 TB/s effective write BW; old layout wrote 256B
// segments at 2KB stride (128 scattered segments per block). New layout: each
// block writes two contiguous 16KB spans. GEMM1's B-staging reads become 1KB
// fully contiguous per wave (was 8x128B at 2KB stride). LDS path unchanged.
__global__ __launch_bounds__(256) void k_gate_trw1(
    const float* __restrict__ x, const float* __restrict__ Wg,
    const float* __restrict__ bg, int* __restrict__ topidx,
    float* __restrict__ topw, int* __restrict__ pos, int* __restrict__ count,
    unsigned short* __restrict__ xb,
    const float* __restrict__ W1, unsigned short* __restrict__ w1t)
{
  if (blockIdx.x < 2048){
    const int bid = blockIdx.x;
    const int e = bid >> 8, rem = bid & 255;
    const int R = DIMD, C = DFFN;         // W1: [1024][4096] -> w1t [16kb][4096n][64k]
    const float* I = W1 + (size_t)e * R * C;
    unsigned short* O = w1t + (size_t)e * R * C;
    const int r0 = (rem >> 5) * 128, c0 = (rem & 31) * 128;  // 8 x 32 tiles
    __shared__ alignas(16) unsigned short tile[128*128];     // 32KB, swizzled slots
    const int tid = threadIdx.x;
    const int qw = tid & 31;              // col-group: cols 4qw..4qw+3
    const int rw = tid >> 5;              // row-within-octet
    #pragma unroll
    for (int it = 0; it < 16; ++it){
      const int r = it * 8 + rw;
      const float4 v = *(const float4*)(I + (size_t)(r0 + r) * C + c0 + qw * 4);
      ushort4 o;
      o.x = f2bf(v.x); o.y = f2bf(v.y); o.z = f2bf(v.z); o.w = f2bf(v.w);
      const int slot = qw ^ ((r >> 2) & 31);
      *(ushort4*)&tile[r * 128 + slot * 4] = o;
    }
    __syncthreads();
    const int p  = tid & 31;              // k-group: k = r0 + 4p..4p+3
    const int cb = tid >> 5;              // 0..7
    const int kb = (r0 >> 6) + (p >> 4);  // k-block index (64-elem blocks)
    const int ki = (4 * p) & 63;          // k within block
    #pragma unroll
    for (int it = 0; it < 4; ++it){
      const int cg = cb * 4 + it;         // out n-group 0..31 (n = c0+4cg..+3)
      const int sl = (cg ^ p) * 4;
      const ushort4 a0 = *(const ushort4*)&tile[(4*p + 0) * 128 + sl];
      const ushort4 a1 = *(const ushort4*)&tile[(4*p + 1) * 128 + sl];
      const ushort4 a2 = *(const ushort4*)&tile[(4*p + 2) * 128 + sl];
      const ushort4 a3 = *(const ushort4*)&tile[(4*p + 3) * 128 + sl];
      ushort4 o;
      o.x = a0.x; o.y = a1.x; o.z = a2.x; o.w = a3.x;
      *(ushort4*)(O + ((size_t)kb * DFFN + (c0 + 4*cg + 0)) * 64 + ki) = o;
      o.x = a0.y; o.y = a1.y; o.z = a2.y; o.w = a3.y;
      *(ushort4*)(O + ((size_t)kb * DFFN + (c0 + 4*cg + 1)) * 64 + ki) = o;
      o.x = a0.z; o.y = a1.z; o.z = a2.z; o.w = a3.z;
      *(ushort4*)(O + ((size_t)kb * DFFN + (c0 + 4*cg + 2)) * 64 + ki) = o;
      o.x = a0.w; o.y = a1.w; o.z = a2.w; o.w = a3.w;
      *(ushort4*)(O + ((size_t)kb * DFFN + (c0 + 4*cg + 3)) * 64 + ki) = o;
    }
    return;
  }
  // ---------------- gating path ----------------
  const int gb = blockIdx.x - 2048;
  const int wid = threadIdx.x >> 6, lane = threadIdx.x & 63;
  const int t = gb * 4 + wid;
  const float* xr = x + (size_t)t * DIMD;
  unsigned short* xbr = xb + (size_t)t * DIMD;
  float acc[NEXP] = {0.f,0.f,0.f,0.f,0.f,0.f,0.f,0.f};
  #pragma unroll
  for (int j = 0; j < DIMD/64; ++j){
    const int d = j*64 + lane;
    const float xv = xr[d];
    xbr[d] = f2bf(xv);                       // fused bf16 conversion
    const float4 wa = *(const float4*)(Wg + (size_t)d*NEXP);
    const float4 wb = *(const float4*)(Wg + (size_t)d*NEXP + 4);
    acc[0] += xv*wa.x; acc[1] += xv*wa.y; acc[2] += xv*wa.z; acc[3] += xv*wa.w;
    acc[4] += xv*wb.x; acc[5] += xv*wb.y; acc[6] += xv*wb.z; acc[7] += xv*wb.w;
  }
  #pragma unroll
  for (int e = 0; e < NEXP; ++e){
    float v = acc[e];
    #pragma unroll
    for (int o = 32; o > 0; o >>= 1) v += __shfl_xor(v, o);
    acc[e] = v;
  }
  if (lane == 0){
    float lg[NEXP], m = -1e30f;
    #pragma unroll
    for (int e = 0; e < NEXP; ++e){ lg[e] = acc[e] + bg[e]; m = fmaxf(m, lg[e]); }
    float p[NEXP], S = 0.f;
    #pragma unroll
    for (int e = 0; e < NEXP; ++e){ p[e] = expf(lg[e] - m); S += p[e]; }
    int e0 = 0;
    #pragma unroll
    for (int e = 1; e < NEXP; ++e) if (p[e] > p[e0]) e0 = e;
    int e1 = (e0 == 0) ? 1 : 0;
    #pragma unroll
    for (int e = 0; e < NEXP; ++e){
      if (e == e0 || e == e1) continue;
      if (p[e] > p[e1]) e1 = e;
    }
    const float denom = p[e0] + p[e1] + 1e-8f * S;   // == top_sum + EPS, scaled by S
    const float w0 = p[e0] / denom, w1 = p[e1] / denom;
    const int p0 = atomicAdd(&count[e0], 1);
    const int p1 = atomicAdd(&count[e1], 1);
    topidx[t*2] = e0; topidx[t*2+1] = e1;
    topw[t*2] = w0;   topw[t*2+1] = w1;
    pos[t*2] = p0;    pos[t*2+1] = p1;
  }
}

// scatter with inline prefix-scan of count (128-aligned padded bases)
__global__ __launch_bounds__(256) void k_scatter(
    const int* __restrict__ topidx, const int* __restrict__ pos,
    const int* __restrict__ count, int* __restrict__ slot_of, int* __restrict__ tok_of)
{
  int basee[NEXP]; int bacc = 0;
  #pragma unroll
  for (int q = 0; q < NEXP; ++q){
    basee[q] = bacc << 7;
    bacc += (count[q] + 127) >> 7;
  }
  const int t = blockIdx.x * 256 + threadIdx.x;
  #pragma unroll
  for (int k = 0; k < 2; ++k){
    const int e = topidx[t*2+k];
    const int g = basee[e] + pos[t*2+k];
    slot_of[t*2+k] = g;
    tok_of[g] = t;
  }
}

// ---------- MFMA GEMM: BM x BN tile, BK=64, 8 waves, single-buffer (R2-proven) ----------
// Expert-chunk XCD mapping (validated R7/R8/R9/R12 via FETCH A/B: XCD ~ hw_id%8).
// R17: GEMM1 (MODE 1) B-source is the k-blocked w1t [16kb][4096n][64k] — per-wave
// staging reads are 1KB fully contiguous (8 adjacent 64-elem rows); K-step offset
// is k0*NT. LDS contents/swizzle/boff unchanged (bit-identical sB). GEMM2 keeps
// the row-major w2t path (control).
// GEMM1 (TRW2=1, 2D grid): g = bx + 16*by < 1152 -> by=9*(g&7)+(g%72)/8, ct=g/72.
// GEMM2 (TRW2=0, 1D grid 576): x=g&7, w=g>>3, by=9x+w%9, ct=(w/9)%CT, ks=(w/9)/CT.
// TRW2=1 also fuses the W2 transpose as extra blocks (by >= NRB128) — R7.
// MODE 1: A gathered via tok_of, epilogue bias+GELU -> bf16 outH
// MODE 2: A slot-contiguous, split-K, bias(ks==0) -> Ys0/Ys1
template<int KD, int KSLICES, int NT, int MODE, int WAVES, int BM, int BN, int MINW, int TRW2>
__global__ __launch_bounds__(WAVES*64, MINW) void k_gemm(
    const unsigned short* __restrict__ A, const unsigned short* __restrict__ Bt,
    const float* __restrict__ bias, const int* __restrict__ tok_of,
    const int* __restrict__ count,
    unsigned short* __restrict__ outH, unsigned short* __restrict__ outY,
    unsigned short* __restrict__ outY1,
    const float* __restrict__ W2src, unsigned short* __restrict__ w2tdst)
{
  __shared__ alignas(16) unsigned short smem[BM*64 + BN*64];   // 48KB, both roles
  constexpr int CT = NT / BN;          // ct values (16 GEMM1, 4 GEMM2)

  int by, ct, ks;
  if constexpr (TRW2 != 0){
    by = blockIdx.y;
    if (by >= NRB128){
      // ---- W2 transpose role: one 128x128 tile, 512 threads ----
      const int bid = (by - NRB128) * gridDim.x + blockIdx.x;    // 0..2047
      const int eT = bid >> 8, rem = bid & 255;
      const int R = DFFN, C = DIMD;         // W2: [4096][1024] -> w2t [1024][4096]
      const float* I = W2src + (size_t)eT * R * C;
      unsigned short* O = w2tdst + (size_t)eT * R * C;
      const int r0 = (rem >> 3) * 128, c0 = (rem & 7) * 128;     // 32 x 8 tiles
      unsigned short* tile = smem;          // 32KB of the 48KB block
      const int tid = threadIdx.x;
      const int qw = tid & 31, rw = tid >> 5;   // rw 0..15
      #pragma unroll
      for (int it = 0; it < 8; ++it){
        const int r = it * 16 + rw;
        const float4 v = *(const float4*)(I + (size_t)(r0 + r) * C + c0 + qw * 4);
        ushort4 o;
        o.x = f2bf(v.x); o.y = f2bf(v.y); o.z = f2bf(v.z); o.w = f2bf(v.w);
        const int slot = qw ^ ((r >> 2) & 31);
        *(ushort4*)&tile[r * 128 + slot * 4] = o;
      }
      __syncthreads();
      const int p = tid & 31, cb = tid >> 5;    // cb 0..15
      #pragma unroll
      for (int it = 0; it < 2; ++it){
        const int cg = cb * 2 + it;             // 0..31
        const int sl = (cg ^ p) * 4;
        const ushort4 a0 = *(const ushort4*)&tile[(4*p + 0) * 128 + sl];
        const ushort4 a1 = *(const ushort4*)&tile[(4*p + 1) * 128 + sl];
        const ushort4 a2 = *(const ushort4*)&tile[(4*p + 2) * 128 + sl];
        const ushort4 a3 = *(const ushort4*)&tile[(4*p + 3) * 128 + sl];
        ushort4 o;
        o.x = a0.x; o.y = a1.x; o.z = a2.x; o.w = a3.x;
        *(ushort4*)(O + (size_t)(c0 + 4*cg + 0) * R + r0 + 4*p) = o;
        o.x = a0.y; o.y = a1.y; o.z = a2.y; o.w = a3.y;
        *(ushort4*)(O + (size_t)(c0 + 4*cg + 1) * R + r0 + 4*p) = o;
        o.x = a0.z; o.y = a1.z; o.z = a2.z; o.w = a3.z;
        *(ushort4*)(O + (size_t)(c0 + 4*cg + 2) * R + r0 + 4*p) = o;
        o.x = a0.w; o.y = a1.w; o.z = a2.w; o.w = a3.w;
        *(ushort4*)(O + (size_t)(c0 + 4*cg + 3) * R + r0 + 4*p) = o;
      }
      return;
    }
    // GEMM1 role: expert-chunk XCD mapping. g in [0, 1152), hw XCD = g%8 = by/9.
    const int g = blockIdx.x + (int)gridDim.x * by;
    by = 9 * (g & 7) + ((g % 72) >> 3);
    ct = g / 72;
    ks = 0;
  } else {
    // GEMM2 role: 1D grid CT*NRB128*KSLICES (=576), expert-chunk XCD mapping.
    static_assert(CT * KSLICES == 8, "GEMM2 map assumes 8 blocks per rowblock");
    const int g = blockIdx.x;
    const int xx = g & 7;
    const int w  = g >> 3;            // [0, 72)
    by = 9 * xx + (w % 9);
    const int cw = w / 9;             // [0, 8)
    ct = cw % CT;
    ks = cw / CT;
  }

  // ---- GEMM role ----
  int e = -1, b0 = 0;
  #pragma unroll
  for (int q = 0; q < NEXP; ++q){
    const int nb = (count[q] + 127) >> 7;
    if (e < 0){ if (by < b0 + nb) e = q; else b0 += nb; }
  }
  if (e < 0) return;
  constexpr int KSL = KD / KSLICES;     // K elements per slice (multiple of 64)
  const int kbase = ks * KSL;
  const int row0 = by * 128;        // global padded slot row (pad-contiguous layout)
  constexpr int T   = WAVES * 64;   // threads
  constexpr int RA  = BM*8 / T;     // A staging rounds
  constexpr int RB  = BN*8 / T;     // B staging rounds
  constexpr int WN  = BN / 64;      // wave-columns (64-wide)
  constexpr int WM  = WAVES / WN;   // wave-rows
  constexpr int MR  = BM / WM / 16; // 16-row fragment repeats per wave
  unsigned short* sA = smem;
  unsigned short* sB = smem + BM*64;
  const int tid = threadIdx.x, wid = tid >> 6, lane = tid & 63;

  // staging: slot s covers row s>>3, global chunk (s&7)^(row&7)
  const unsigned short* aptr[RA];
  #pragma unroll
  for (int i = 0; i < RA; ++i){
    const int s = i*T + tid;
    const int row = s >> 3;
    const int c = (s & 7) ^ (row & 7);
    size_t arow;
    if (MODE == 1) arow = (size_t)tok_of[row0 + row] * KD;
    else           arow = (size_t)(row0 + row) * KD;
    aptr[i] = A + arow + kbase + c*8;
  }
  const unsigned short* bptr[RB];
  #pragma unroll
  for (int i = 0; i < RB; ++i){
    const int s = i*T + tid;
    const int row = s >> 3;
    const int c = (s & 7) ^ (row & 7);
    if (MODE == 1)
      bptr[i] = Bt + (size_t)e*NT*KD + (size_t)(ct*BN + row)*64 + c*8;  // [kb][n][64]
    else
      bptr[i] = Bt + ((size_t)e*NT + ct*BN + row) * KD + kbase + c*8;
  }

  f32x4 acc[MR][4] = {};
  const int wr = wid / WN, wc = wid % WN;   // wave tile (MR*16) x 64

  int aoff[MR][2], boff[4][2];
  #pragma unroll
  for (int m = 0; m < MR; ++m){
    #pragma unroll
    for (int s = 0; s < 2; ++s){
      const int rowA = wr*(MR*16) + m*16 + (lane & 15);
      aoff[m][s] = rowA*64 + (((s*4) + (lane >> 4)) ^ (rowA & 7))*8;
    }
  }
  #pragma unroll
  for (int n = 0; n < 4; ++n){
    #pragma unroll
    for (int s = 0; s < 2; ++s){
      const int rowB = wc*64 + n*16 + (lane & 15);
      boff[n][s] = rowB*64 + (((s*4) + (lane >> 4)) ^ (rowB & 7))*8;
    }
  }

  for (int k0 = 0; k0 < KSL; k0 += 64){
    const size_t bstep = (MODE == 1) ? (size_t)k0 * NT : (size_t)k0;
    #pragma unroll
    for (int i = 0; i < RA; ++i)
      gload_lds16(aptr[i] + k0, &sA[(i*T + tid - lane)*8]);
    #pragma unroll
    for (int i = 0; i < RB; ++i)
      gload_lds16(bptr[i] + bstep, &sB[(i*T + tid - lane)*8]);
    __syncthreads();
    #pragma unroll
    for (int s = 0; s < 2; ++s){
      bf16x8 af[MR], bfr[4];
      #pragma unroll
      for (int m = 0; m < MR; ++m) af[m] = *(const bf16x8*)&sA[aoff[m][s]];
      #pragma unroll
      for (int n = 0; n < 4; ++n) bfr[n] = *(const bf16x8*)&sB[boff[n][s]];
      #pragma unroll
      for (int m = 0; m < MR; ++m)
        #pragma unroll
        for (int n = 0; n < 4; ++n)
          acc[m][n] = __builtin_amdgcn_mfma_f32_16x16x32_bf16(af[m], bfr[n], acc[m][n], 0, 0, 0);
    }
    __syncthreads();
  }

  const float* be = bias + (size_t)e * NT;
  unsigned short* outYs = (ks == 0) ? outY : outY1;
  #pragma unroll
  for (int m = 0; m < MR; ++m){
    #pragma unroll
    for (int n = 0; n < 4; ++n){
      #pragma unroll
      for (int j = 0; j < 4; ++j){
        const int rl = wr*(MR*16) + m*16 + ((lane >> 4) << 2) + j;  // C row = (l>>4)*4+j
        const int ng = ct*BN + wc*64 + n*16 + (lane & 15);          // C col = l&15
        const size_t orow = (size_t)(row0 + rl) * NT + ng;          // pad rows: harmless
        if (MODE == 1){
          const float u = acc[m][n][j] + be[ng];
          // tanh-form GELU (|diff from exact| <~3e-3, << bf16 rounding of Hs)
          float y = 0.7978845608028654f * (u + 0.044715f * u * u * u);
          y = fminf(fmaxf(y, -15.f), 15.f);
          const float ex = __expf(2.f * y);
          const float th = (ex - 1.f) / (ex + 1.f);
          outH[orow] = f2bf(0.5f * u * (1.f + th));
        } else {
          outYs[orow] = f2bf(acc[m][n][j] + ((ks == 0) ? be[ng] : 0.f));
        }
      }
    }
  }
}

// ---------------- combine top-2 (sum bf16 split-K partials) + LayerNorm ----------------
__global__ __launch_bounds__(256) void k_combine_ln(
    const unsigned short* __restrict__ Ys0, const unsigned short* __restrict__ Ys1,
    const int* __restrict__ slot_of,
    const float* __restrict__ topw, const float* __restrict__ gamma,
    const float* __restrict__ beta, float* __restrict__ out)
{
  const int t = blockIdx.x;
  const int g0 = slot_of[t*2], g1 = slot_of[t*2+1];
  const float w0 = topw[t*2], w1 = topw[t*2+1];
  const int c = threadIdx.x;
  const ushort4 a0 = *(const ushort4*)(Ys0 + (size_t)g0*DIMD + c*4);
  const ushort4 a1 = *(const ushort4*)(Ys1 + (size_t)g0*DIMD + c*4);
  const ushort4 b0 = *(const ushort4*)(Ys0 + (size_t)g1*DIMD + c*4);
  const ushort4 b1 = *(const ushort4*)(Ys1 + (size_t)g1*DIMD + c*4);
  float4 v;
  v.x = w0*(bf2f(a0.x)+bf2f(a1.x)) + w1*(bf2f(b0.x)+bf2f(b1.x));
  v.y = w0*(bf2f(a0.y)+bf2f(a1.y)) + w1*(bf2f(b0.y)+bf2f(b1.y));
  v.z = w0*(bf2f(a0.z)+bf2f(a1.z)) + w1*(bf2f(b0.z)+bf2f(b1.z));
  v.w = w0*(bf2f(a0.w)+bf2f(a1.w)) + w1*(bf2f(b0.w)+bf2f(b1.w));
  float s  = v.x + v.y + v.z + v.w;
  float ss = v.x*v.x + v.y*v.y + v.z*v.z + v.w*v.w;
  #pragma unroll
  for (int o = 32; o > 0; o >>= 1){ s += __shfl_xor(s, o); ss += __shfl_xor(ss, o); }
  __shared__ float red[8];
  const int wid = threadIdx.x >> 6, lane = threadIdx.x & 63;
  if (lane == 0){ red[wid] = s; red[4 + wid] = ss; }
  __syncthreads();
  const float S  = red[0] + red[1] + red[2] + red[3];
  const float SS = red[4] + red[5] + red[6] + red[7];
  const float mu  = S * (1.f/DIMD);
  const float var = SS * (1.f/DIMD) - mu*mu;
  const float inv = rsqrtf(var + 1e-5f);
  const float4 gm = *(const float4*)(gamma + c*4);
  const float4 bt = *(const float4*)(beta + c*4);
  float4 o;
  o.x = (v.x - mu)*inv*gm.x + bt.x;
  o.y = (v.y - mu)*inv*gm.y + bt.y;
  o.z = (v.z - mu)*inv*gm.z + bt.z;
  o.w = (v.w - mu)*inv*gm.w + bt.w;
  *(float4*)(out + (size_t)t*DIMD + c*4) = o;
}

extern "C" void kernel_launch(void* const* d_in, const int* in_sizes, int n_in,
                              void* d_out, int out_size, void* d_ws, size_t ws_size,
                              hipStream_t stream)
{
  const float* x     = (const float*)d_in[0];
  const float* Wg    = (const float*)d_in[1];
  const float* bg    = (const float*)d_in[2];
  const float* W1    = (const float*)d_in[3];
  const float* b1    = (const float*)d_in[4];
  const float* W2    = (const float*)d_in[5];
  const float* b2    = (const float*)d_in[6];
  const float* gamma = (const float*)d_in[7];
  const float* beta  = (const float*)d_in[8];
  float* out = (float*)d_out;

  char* ws = (char*)d_ws;
  size_t off = 0;
  auto alloc = [&](size_t b){ char* p = ws + off; off += (b + 255) & ~(size_t)255; return p; };
  unsigned short* xb  = (unsigned short*)alloc((size_t)TOK*DIMD*2);
  unsigned short* w1t = (unsigned short*)alloc((size_t)NEXP*DFFN*DIMD*2);
  unsigned short* w2t = (unsigned short*)alloc((size_t)NEXP*DIMD*DFFN*2);
  unsigned short* Hs  = (unsigned short*)alloc((size_t)NSLOT*DFFN*2);
  int*   topidx  = (int*)alloc(TOK*2*4);
  float* topw    = (float*)alloc(TOK*2*4);
  int*   pos     = (int*)alloc(TOK*2*4);
  int*   slot_of = (int*)alloc(TOK*2*4);
  int*   tok_of  = (int*)alloc(NSLOT*4);
  int*   count   = (int*)alloc(256);
  // split-K bf16 partials alias w1t (dead after GEMM1): 2 x 18.9MB = 37.8MB <= 64MB region.
  // w1t is read ONLY by GEMM1 (stream-ordered complete before GEMM2 writes the partials).
  unsigned short* Ys0b = (unsigned short*)w1t;
  unsigned short* Ys1b = Ys0b + (size_t)NSLOT*DIMD;

  (void)hipMemsetAsync(count, 0, NEXP*sizeof(int), stream);
  (void)hipMemsetAsync(tok_of, 0, NSLOT*sizeof(int), stream);  // pad rows -> token 0
  // Dispatch 1: W1 transpose (2048 blocks, k-blocked contiguous writes) +
  // gating (1024 blocks), fused.
  k_gate_trw1<<<3072, 256, 0, stream>>>(x, Wg, bg, topidx, topw, pos, count, xb, W1, w1t);
  k_scatter<<<TOK/256, 256, 0, stream>>>(topidx, pos, count, slot_of, tok_of);
  // GEMM1 (by<72, expert-chunk XCD map, k-blocked B) + W2 transpose (by 72..199).
  k_gemm<DIMD, 1, DFFN, 1, 8, 128, 256, 4, 1><<<dim3(DFFN/256, NRB128 + 128), 512, 0, stream>>>(
      xb, w1t, b1, tok_of, count, Hs, nullptr, nullptr, W2, w2t);
  // GEMM2: 1D grid 576, expert-chunk XCD map.
  k_gemm<DFFN, 2, DIMD, 2, 8, 128, 256, 4, 0><<<dim3((DIMD/256)*NRB128*2), 512, 0, stream>>>(
      Hs, w2t, b2, tok_of, count, nullptr, Ys0b, Ys1b, nullptr, nullptr);
  k_combine_ln<<<TOK, 256, 0, stream>>>(Ys0b, Ys1b, slot_of, topw, gamma, beta, out);
}

// Round 18
// 387.598 us; speedup vs baseline: 1.0698x; 1.0004x over previous
//
#include <hip/hip_runtime.h>
#include <hip/hip_bf16.h>

#define TOK  4096
#define DIMD 1024
#define NEXP 8
#define DFFN 4096
#define NSLOT   (TOK*2 + NEXP*128)       /* 9216 padded slots (128-aligned bases) */
#define NRB128  ((TOK*2)/128 + NEXP)     /* 72 worst-case 128-rowblocks */

typedef __attribute__((ext_vector_type(8))) short bf16x8;
typedef __attribute__((ext_vector_type(4))) float f32x4;

__device__ __forceinline__ unsigned short f2bf(float f){
  unsigned int u = __float_as_uint(f);
  unsigned int r = u + 0x7FFFu + ((u >> 16) & 1u);   // RNE (finite values only here)
  return (unsigned short)(r >> 16);
}

__device__ __forceinline__ float bf2f(unsigned short h){
  unsigned int u = ((unsigned int)h) << 16;
  return __uint_as_float(u);
}

__device__ __forceinline__ void gload_lds16(const void* g, void* l){
  __builtin_amdgcn_global_load_lds(
      (const __attribute__((address_space(1))) unsigned int*)g,
      (__attribute__((address_space(3))) unsigned int*)l, 16, 0, 0);
}

// ---- fused: W1 transpose (blocks 0..4095) + gating (blocks 4096..5119).
// R18: transpose phase 1 now uses ASYNC global_load_lds DMA (Common-mistake #1:
// every prior variant staged global->VGPR->cvt->LDS; hipcc serializes that chain
// regardless of register budget — R16). 128k x 64n fp32 tile (32KB LDS), 8
// back-to-back DMA issues, zero VGPR deps. Source chunk pre-swizzled
// c ^ ((r>>3)&7) (both-sides rule, LDS dest linear); phase 2 reads are exactly
// 2 lanes/bank (free), cvt f2bf, 1KB-contiguous wave stores into the R17
// k-blocked w1t [16kb][4096n][64k] (bit-identical contents).
__global__ __launch_bounds__(256) void k_gate_trw1(
    const float* __restrict__ x, const float* __restrict__ Wg,
    const float* __restrict__ bg, int* __restrict__ topidx,
    float* __restrict__ topw, int* __restrict__ pos, int* __restrict__ count,
    unsigned short* __restrict__ xb,
    const float* __restrict__ W1, unsigned short* __restrict__ w1t)
{
  if (blockIdx.x < 4096){
    const int bid = blockIdx.x;
    const int e = bid >> 9, rem = bid & 511;        // 8 k-tiles x 64 n-tiles
    const int r0 = (rem >> 6) << 7;                 // k-tile base (128)
    const int c0 = (rem & 63) << 6;                 // n-tile base (64)
    const int kb0 = r0 >> 6;                        // first 64-k block
    const float* I = W1 + (size_t)e * DIMD * DFFN;
    unsigned short* O = w1t + (size_t)e * DIMD * DFFN;
    __shared__ alignas(16) float tileF[128*64];     // 32KB fp32, swizzled chunks
    const int tid = threadIdx.x, lane = tid & 63;
    // ---- phase 1: 8 async DMA loads; LDS slot (r, c) holds global chunk c^phi(r)
    #pragma unroll
    for (int it = 0; it < 8; ++it){
      const int chunk = it*256 + tid;               // 0..2047
      const int r = chunk >> 4;                     // local k-row 0..127
      const int c = chunk & 15;                     // 16B chunk in row
      const int cs = c ^ ((r >> 3) & 7);            // pre-swizzled source chunk
      gload_lds16(I + (size_t)(r0 + r) * DFFN + c0 + cs*4,
                  &tileF[(size_t)(it*256 + tid - lane) * 4]);
    }
    __syncthreads();
    // ---- phase 2: cvt + store. thread: o = ki-octet, nb0 = n within 32-group.
    const int o   = tid & 7;
    const int nb0 = (tid >> 3) & 31;
    #pragma unroll
    for (int p = 0; p < 4; ++p){
      const int nloc = (p & 1)*32 + nb0;            // 0..63
      const int hb = p >> 1;                        // k half (0/1)
      const int sc = (nloc >> 2) ^ o;               // swizzled chunk (phi(r)=o)
      bf16x8 v;
      #pragma unroll
      for (int i = 0; i < 8; ++i){
        const float f = tileF[(size_t)(hb*64 + o*8 + i)*64 + sc*4 + (nloc & 3)];
        v[i] = (short)f2bf(f);
      }
      *(bf16x8*)&O[((size_t)(kb0 + hb)*DFFN + (c0 + nloc))*64 + o*8] = v;
    }
    return;
  }
  // ---------------- gating path ----------------
  const int gb = blockIdx.x - 4096;
  const int wid = threadIdx.x >> 6, lane = threadIdx.x & 63;
  const int t = gb * 4 + wid;
  const float* xr = x + (size_t)t * DIMD;
  unsigned short* xbr = xb + (size_t)t * DIMD;
  float acc[NEXP] = {0.f,0.f,0.f,0.f,0.f,0.f,0.f,0.f};
  #pragma unroll
  for (int j = 0; j < DIMD/64; ++j){
    const int d = j*64 + lane;
    const float xv = xr[d];
    xbr[d] = f2bf(xv);                       // fused bf16 conversion
    const float4 wa = *(const float4*)(Wg + (size_t)d*NEXP);
    const float4 wb = *(const float4*)(Wg + (size_t)d*NEXP + 4);
    acc[0] += xv*wa.x; acc[1] += xv*wa.y; acc[2] += xv*wa.z; acc[3] += xv*wa.w;
    acc[4] += xv*wb.x; acc[5] += xv*wb.y; acc[6] += xv*wb.z; acc[7] += xv*wb.w;
  }
  #pragma unroll
  for (int e = 0; e < NEXP; ++e){
    float v = acc[e];
    #pragma unroll
    for (int o = 32; o > 0; o >>= 1) v += __shfl_xor(v, o);
    acc[e] = v;
  }
  if (lane == 0){
    float lg[NEXP], m = -1e30f;
    #pragma unroll
    for (int e = 0; e < NEXP; ++e){ lg[e] = acc[e] + bg[e]; m = fmaxf(m, lg[e]); }
    float p[NEXP], S = 0.f;
    #pragma unroll
    for (int e = 0; e < NEXP; ++e){ p[e] = expf(lg[e] - m); S += p[e]; }
    int e0 = 0;
    #pragma unroll
    for (int e = 1; e < NEXP; ++e) if (p[e] > p[e0]) e0 = e;
    int e1 = (e0 == 0) ? 1 : 0;
    #pragma unroll
    for (int e = 0; e < NEXP; ++e){
      if (e == e0 || e == e1) continue;
      if (p[e] > p[e1]) e1 = e;
    }
    const float denom = p[e0] + p[e1] + 1e-8f * S;   // == top_sum + EPS, scaled by S
    const float w0 = p[e0] / denom, w1 = p[e1] / denom;
    const int p0 = atomicAdd(&count[e0], 1);
    const int p1 = atomicAdd(&count[e1], 1);
    topidx[t*2] = e0; topidx[t*2+1] = e1;
    topw[t*2] = w0;   topw[t*2+1] = w1;
    pos[t*2] = p0;    pos[t*2+1] = p1;
  }
}

// scatter with inline prefix-scan of count (128-aligned padded bases)
__global__ __launch_bounds__(256) void k_scatter(
    const int* __restrict__ topidx, const int* __restrict__ pos,
    const int* __restrict__ count, int* __restrict__ slot_of, int* __restrict__ tok_of)
{
  int basee[NEXP]; int bacc = 0;
  #pragma unroll
  for (int q = 0; q < NEXP; ++q){
    basee[q] = bacc << 7;
    bacc += (count[q] + 127) >> 7;
  }
  const int t = blockIdx.x * 256 + threadIdx.x;
  #pragma unroll
  for (int k = 0; k < 2; ++k){
    const int e = topidx[t*2+k];
    const int g = basee[e] + pos[t*2+k];
    slot_of[t*2+k] = g;
    tok_of[g] = t;
  }
}

// ---------- MFMA GEMM: BM x BN tile, BK=64, 8 waves, single-buffer (R2-proven) ----------
// Expert-chunk XCD mapping (validated R7/R8/R9/R12 via FETCH A/B: XCD ~ hw_id%8).
// GEMM1 (MODE 1) B-source: k-blocked w1t [16kb][4096n][64k] (R17, +7us) — per-wave
// staging reads 1KB contiguous; K-step offset k0*NT. GEMM2 row-major w2t.
// GEMM1 (TRW2=1, 2D grid): g = bx + 16*by < 1152 -> by=9*(g&7)+(g%72)/8, ct=g/72.
// GEMM2 (TRW2=0, 1D grid 576): x=g&7, w=g>>3, by=9x+w%9, ct=(w/9)%CT, ks=(w/9)/CT.
// TRW2=1 also fuses the W2 transpose as extra blocks (by >= NRB128) — R7.
// MODE 1: A gathered via tok_of, epilogue bias+GELU -> bf16 outH
// MODE 2: A slot-contiguous, split-K, bias(ks==0) -> Ys0/Ys1
template<int KD, int KSLICES, int NT, int MODE, int WAVES, int BM, int BN, int MINW, int TRW2>
__global__ __launch_bounds__(WAVES*64, MINW) void k_gemm(
    const unsigned short* __restrict__ A, const unsigned short* __restrict__ Bt,
    const float* __restrict__ bias, const int* __restrict__ tok_of,
    const int* __restrict__ count,
    unsigned short* __restrict__ outH, unsigned short* __restrict__ outY,
    unsigned short* __restrict__ outY1,
    const float* __restrict__ W2src, unsigned short* __restrict__ w2tdst)
{
  __shared__ alignas(16) unsigned short smem[BM*64 + BN*64];   // 48KB, both roles
  constexpr int CT = NT / BN;          // ct values (16 GEMM1, 4 GEMM2)

  int by, ct, ks;
  if constexpr (TRW2 != 0){
    by = blockIdx.y;
    if (by >= NRB128){
      // ---- W2 transpose role: one 128x128 tile, 512 threads ----
      const int bid = (by - NRB128) * gridDim.x + blockIdx.x;    // 0..2047
      const int eT = bid >> 8, rem = bid & 255;
      const int R = DFFN, C = DIMD;         // W2: [4096][1024] -> w2t [1024][4096]
      const float* I = W2src + (size_t)eT * R * C;
      unsigned short* O = w2tdst + (size_t)eT * R * C;
      const int r0 = (rem >> 3) * 128, c0 = (rem & 7) * 128;     // 32 x 8 tiles
      unsigned short* tile = smem;          // 32KB of the 48KB block
      const int tid = threadIdx.x;
      const int qw = tid & 31, rw = tid >> 5;   // rw 0..15
      #pragma unroll
      for (int it = 0; it < 8; ++it){
        const int r = it * 16 + rw;
        const float4 v = *(const float4*)(I + (size_t)(r0 + r) * C + c0 + qw * 4);
        ushort4 o;
        o.x = f2bf(v.x); o.y = f2bf(v.y); o.z = f2bf(v.z); o.w = f2bf(v.w);
        const int slot = qw ^ ((r >> 2) & 31);
        *(ushort4*)&tile[r * 128 + slot * 4] = o;
      }
      __syncthreads();
      const int p = tid & 31, cb = tid >> 5;    // cb 0..15
      #pragma unroll
      for (int it = 0; it < 2; ++it){
        const int cg = cb * 2 + it;             // 0..31
        const int sl = (cg ^ p) * 4;
        const ushort4 a0 = *(const ushort4*)&tile[(4*p + 0) * 128 + sl];
        const ushort4 a1 = *(const ushort4*)&tile[(4*p + 1) * 128 + sl];
        const ushort4 a2 = *(const ushort4*)&tile[(4*p + 2) * 128 + sl];
        const ushort4 a3 = *(const ushort4*)&tile[(4*p + 3) * 128 + sl];
        ushort4 o;
        o.x = a0.x; o.y = a1.x; o.z = a2.x; o.w = a3.x;
        *(ushort4*)(O + (size_t)(c0 + 4*cg + 0) * R + r0 + 4*p) = o;
        o.x = a0.y; o.y = a1.y; o.z = a2.y; o.w = a3.y;
        *(ushort4*)(O + (size_t)(c0 + 4*cg + 1) * R + r0 + 4*p) = o;
        o.x = a0.z; o.y = a1.z; o.z = a2.z; o.w = a3.z;
        *(ushort4*)(O + (size_t)(c0 + 4*cg + 2) * R + r0 + 4*p) = o;
        o.x = a0.w; o.y = a1.w; o.z = a2.w; o.w = a3.w;
        *(ushort4*)(O + (size_t)(c0 + 4*cg + 3) * R + r0 + 4*p) = o;
      }
      return;
    }
    // GEMM1 role: expert-chunk XCD mapping. g in [0, 1152), hw XCD = g%8 = by/9.
    const int g = blockIdx.x + (int)gridDim.x * by;
    by = 9 * (g & 7) + ((g % 72) >> 3);
    ct = g / 72;
    ks = 0;
  } else {
    // GEMM2 role: 1D grid CT*NRB128*KSLICES (=576), expert-chunk XCD mapping.
    static_assert(CT * KSLICES == 8, "GEMM2 map assumes 8 blocks per rowblock");
    const int g = blockIdx.x;
    const int xx = g & 7;
    const int w  = g >> 3;            // [0, 72)
    by = 9 * xx + (w % 9);
    const int cw = w / 9;             // [0, 8)
    ct = cw % CT;
    ks = cw / CT;
  }

  // ---- GEMM role ----
  int e = -1, b0 = 0;
  #pragma unroll
  for (int q = 0; q < NEXP; ++q){
    const int nb = (count[q] + 127) >> 7;
    if (e < 0){ if (by < b0 + nb) e = q; else b0 += nb; }
  }
  if (e < 0) return;
  constexpr int KSL = KD / KSLICES;     // K elements per slice (multiple of 64)
  const int kbase = ks * KSL;
  const int row0 = by * 128;        // global padded slot row (pad-contiguous layout)
  constexpr int T   = WAVES * 64;   // threads
  constexpr int RA  = BM*8 / T;     // A staging rounds
  constexpr int RB  = BN*8 / T;     // B staging rounds
  constexpr int WN  = BN / 64;      // wave-columns (64-wide)
  constexpr int WM  = WAVES / WN;   // wave-rows
  constexpr int MR  = BM / WM / 16; // 16-row fragment repeats per wave
  unsigned short* sA = smem;
  unsigned short* sB = smem + BM*64;
  const int tid = threadIdx.x, wid = tid >> 6, lane = tid & 63;

  // staging: slot s covers row s>>3, global chunk (s&7)^(row&7)
  const unsigned short* aptr[RA];
  #pragma unroll
  for (int i = 0; i < RA; ++i){
    const int s = i*T + tid;
    const int row = s >> 3;
    const int c = (s & 7) ^ (row & 7);
    size_t arow;
    if (MODE == 1) arow = (size_t)tok_of[row0 + row] * KD;
    else           arow = (size_t)(row0 + row) * KD;
    aptr[i] = A + arow + kbase + c*8;
  }
  const unsigned short* bptr[RB];
  #pragma unroll
  for (int i = 0; i < RB; ++i){
    const int s = i*T + tid;
    const int row = s >> 3;
    const int c = (s & 7) ^ (row & 7);
    if (MODE == 1)
      bptr[i] = Bt + (size_t)e*NT*KD + (size_t)(ct*BN + row)*64 + c*8;  // [kb][n][64]
    else
      bptr[i] = Bt + ((size_t)e*NT + ct*BN + row) * KD + kbase + c*8;
  }

  f32x4 acc[MR][4] = {};
  const int wr = wid / WN, wc = wid % WN;   // wave tile (MR*16) x 64

  int aoff[MR][2], boff[4][2];
  #pragma unroll
  for (int m = 0; m < MR; ++m){
    #pragma unroll
    for (int s = 0; s < 2; ++s){
      const int rowA = wr*(MR*16) + m*16 + (lane & 15);
      aoff[m][s] = rowA*64 + (((s*4) + (lane >> 4)) ^ (rowA & 7))*8;
    }
  }
  #pragma unroll
  for (int n = 0; n < 4; ++n){
    #pragma unroll
    for (int s = 0; s < 2; ++s){
      const int rowB = wc*64 + n*16 + (lane & 15);
      boff[n][s] = rowB*64 + (((s*4) + (lane >> 4)) ^ (rowB & 7))*8;
    }
  }

  for (int k0 = 0; k0 < KSL; k0 += 64){
    const size_t bstep = (MODE == 1) ? (size_t)k0 * NT : (size_t)k0;
    #pragma unroll
    for (int i = 0; i < RA; ++i)
      gload_lds16(aptr[i] + k0, &sA[(i*T + tid - lane)*8]);
    #pragma unroll
    for (int i = 0; i < RB; ++i)
      gload_lds16(bptr[i] + bstep, &sB[(i*T + tid - lane)*8]);
    __syncthreads();
    #pragma unroll
    for (int s = 0; s < 2; ++s){
      bf16x8 af[MR], bfr[4];
      #pragma unroll
      for (int m = 0; m < MR; ++m) af[m] = *(const bf16x8*)&sA[aoff[m][s]];
      #pragma unroll
      for (int n = 0; n < 4; ++n) bfr[n] = *(const bf16x8*)&sB[boff[n][s]];
      #pragma unroll
      for (int m = 0; m < MR; ++m)
        #pragma unroll
        for (int n = 0; n < 4; ++n)
          acc[m][n] = __builtin_amdgcn_mfma_f32_16x16x32_bf16(af[m], bfr[n], acc[m][n], 0, 0, 0);
    }
    __syncthreads();
  }

  const float* be = bias + (size_t)e * NT;
  unsigned short* outYs = (ks == 0) ? outY : outY1;
  #pragma unroll
  for (int m = 0; m < MR; ++m){
    #pragma unroll
    for (int n = 0; n < 4; ++n){
      #pragma unroll
      for (int j = 0; j < 4; ++j){
        const int rl = wr*(MR*16) + m*16 + ((lane >> 4) << 2) + j;  // C row = (l>>4)*4+j
        const int ng = ct*BN + wc*64 + n*16 + (lane & 15);          // C col = l&15
        const size_t orow = (size_t)(row0 + rl) * NT + ng;          // pad rows: harmless
        if (MODE == 1){
          const float u = acc[m][n][j] + be[ng];
          // tanh-form GELU (|diff from exact| <~3e-3, << bf16 rounding of Hs)
          float y = 0.7978845608028654f * (u + 0.044715f * u * u * u);
          y = fminf(fmaxf(y, -15.f), 15.f);
          const float ex = __expf(2.f * y);
          const float th = (ex - 1.f) / (ex + 1.f);
          outH[orow] = f2bf(0.5f * u * (1.f + th));
        } else {
          outYs[orow] = f2bf(acc[m][n][j] + ((ks == 0) ? be[ng] : 0.f));
        }
      }
    }
  }
}

// ---------------- combine top-2 (sum bf16 split-K partials) + LayerNorm ----------------
__global__ __launch_bounds__(256) void k_combine_ln(
    const unsigned short* __restrict__ Ys0, const unsigned short* __restrict__ Ys1,
    const int* __restrict__ slot_of,
    const float* __restrict__ topw, const float* __restrict__ gamma,
    const float* __restrict__ beta, float* __restrict__ out)
{
  const int t = blockIdx.x;
  const int g0 = slot_of[t*2], g1 = slot_of[t*2+1];
  const float w0 = topw[t*2], w1 = topw[t*2+1];
  const int c = threadIdx.x;
  const ushort4 a0 = *(const ushort4*)(Ys0 + (size_t)g0*DIMD + c*4);
  const ushort4 a1 = *(const ushort4*)(Ys1 + (size_t)g0*DIMD + c*4);
  const ushort4 b0 = *(const ushort4*)(Ys0 + (size_t)g1*DIMD + c*4);
  const ushort4 b1 = *(const ushort4*)(Ys1 + (size_t)g1*DIMD + c*4);
  float4 v;
  v.x = w0*(bf2f(a0.x)+bf2f(a1.x)) + w1*(bf2f(b0.x)+bf2f(b1.x));
  v.y = w0*(bf2f(a0.y)+bf2f(a1.y)) + w1*(bf2f(b0.y)+bf2f(b1.y));
  v.z = w0*(bf2f(a0.z)+bf2f(a1.z)) + w1*(bf2f(b0.z)+bf2f(b1.z));
  v.w = w0*(bf2f(a0.w)+bf2f(a1.w)) + w1*(bf2f(b0.w)+bf2f(b1.w));
  float s  = v.x + v.y + v.z + v.w;
  float ss = v.x*v.x + v.y*v.y + v.z*v.z + v.w*v.w;
  #pragma unroll
  for (int o = 32; o > 0; o >>= 1){ s += __shfl_xor(s, o); ss += __shfl_xor(ss, o); }
  __shared__ float red[8];
  const int wid = threadIdx.x >> 6, lane = threadIdx.x & 63;
  if (lane == 0){ red[wid] = s; red[4 + wid] = ss; }
  __syncthreads();
  const float S  = red[0] + red[1] + red[2] + red[3];
  const float SS = red[4] + red[5] + red[6] + red[7];
  const float mu  = S * (1.f/DIMD);
  const float var = SS * (1.f/DIMD) - mu*mu;
  const float inv = rsqrtf(var + 1e-5f);
  const float4 gm = *(const float4*)(gamma + c*4);
  const float4 bt = *(const float4*)(beta + c*4);
  float4 o;
  o.x = (v.x - mu)*inv*gm.x + bt.x;
  o.y = (v.y - mu)*inv*gm.y + bt.y;
  o.z = (v.z - mu)*inv*gm.z + bt.z;
  o.w = (v.w - mu)*inv*gm.w + bt.w;
  *(float4*)(out + (size_t)t*DIMD + c*4) = o;
}

extern "C" void kernel_launch(void* const* d_in, const int* in_sizes, int n_in,
                              void* d_out, int out_size, void* d_ws, size_t ws_size,
                              hipStream_t stream)
{
  const float* x     = (const float*)d_in[0];
  const float* Wg    = (const float*)d_in[1];
  const float* bg    = (const float*)d_in[2];
  const float* W1    = (const float*)d_in[3];
  const float* b1    = (const float*)d_in[4];
  const float* W2    = (const float*)d_in[5];
  const float* b2    = (const float*)d_in[6];
  const float* gamma = (const float*)d_in[7];
  const float* beta  = (const float*)d_in[8];
  float* out = (float*)d_out;

  char* ws = (char*)d_ws;
  size_t off = 0;
  auto alloc = [&](size_t b){ char* p = ws + off; off += (b + 255) & ~(size_t)255; return p; };
  unsigned short* xb  = (unsigned short*)alloc((size_t)TOK*DIMD*2);
  unsigned short* w1t = (unsigned short*)alloc((size_t)NEXP*DFFN*DIMD*2);
  unsigned short* w2t = (unsigned short*)alloc((size_t)NEXP*DIMD*DFFN*2);
  unsigned short* Hs  = (unsigned short*)alloc((size_t)NSLOT*DFFN*2);
  int*   topidx  = (int*)alloc(TOK*2*4);
  float* topw    = (float*)alloc(TOK*2*4);
  int*   pos     = (int*)alloc(TOK*2*4);
  int*   slot_of = (int*)alloc(TOK*2*4);
  int*   tok_of  = (int*)alloc(NSLOT*4);
  int*   count   = (int*)alloc(256);
  // split-K bf16 partials alias w1t (dead after GEMM1): 2 x 18.9MB = 37.8MB <= 64MB region.
  // w1t is read ONLY by GEMM1 (stream-ordered complete before GEMM2 writes the partials).
  unsigned short* Ys0b = (unsigned short*)w1t;
  unsigned short* Ys1b = Ys0b + (size_t)NSLOT*DIMD;

  (void)hipMemsetAsync(count, 0, NEXP*sizeof(int), stream);
  (void)hipMemsetAsync(tok_of, 0, NSLOT*sizeof(int), stream);  // pad rows -> token 0
  // Dispatch 1: W1 transpose (4096 blocks, async-DMA phase 1) + gating (1024).
  k_gate_trw1<<<5120, 256, 0, stream>>>(x, Wg, bg, topidx, topw, pos, count, xb, W1, w1t);
  k_scatter<<<TOK/256, 256, 0, stream>>>(topidx, pos, count, slot_of, tok_of);
  // GEMM1 (by<72, expert-chunk XCD map, k-blocked B) + W2 transpose (by 72..199).
  k_gemm<DIMD, 1, DFFN, 1, 8, 128, 256, 4, 1><<<dim3(DFFN/256, NRB128 + 128), 512, 0, stream>>>(
      xb, w1t, b1, tok_of, count, Hs, nullptr, nullptr, W2, w2t);
  // GEMM2: 1D grid 576, expert-chunk XCD map.
  k_gemm<DFFN, 2, DIMD, 2, 8, 128, 256, 4, 0><<<dim3((DIMD/256)*NRB128*2), 512, 0, stream>>>(
      Hs, w2t, b2, tok_of, count, nullptr, Ys0b, Ys1b, nullptr, nullptr);
  k_combine_ln<<<TOK, 256, 0, stream>>>(Ys0b, Ys1b, slot_of, topw, gamma, beta, out);
}